// Round 2
// baseline (479.704 us; speedup 1.0000x reference)
//
#include <hip/hip_runtime.h>
#include <hip/hip_bf16.h>

// Problem constants
#define NB 2
#define SEQ 2048
#define HEADS 16
#define HD 64
#define ED 1024

typedef __bf16 bf16x8 __attribute__((ext_vector_type(8)));
typedef float f32x4 __attribute__((ext_vector_type(4)));
typedef unsigned short u16x8 __attribute__((ext_vector_type(8)));
typedef unsigned short u16x4 __attribute__((ext_vector_type(4)));

__device__ __forceinline__ unsigned short f2bf(float f) {
    unsigned u = __builtin_bit_cast(unsigned, f);
    u += 0x7fffu + ((u >> 16) & 1u);   // RNE
    return (unsigned short)(u >> 16);
}

// load 8 fp32, convert to bf16x8 fragment
__device__ __forceinline__ bf16x8 cvt8(const float* __restrict__ p) {
    const float4* p4 = (const float4*)p;
    float4 a = p4[0], b = p4[1];
    u16x8 u;
    u[0] = f2bf(a.x); u[1] = f2bf(a.y); u[2] = f2bf(a.z); u[3] = f2bf(a.w);
    u[4] = f2bf(b.x); u[5] = f2bf(b.y); u[6] = f2bf(b.z); u[7] = f2bf(b.w);
    return __builtin_bit_cast(bf16x8, u);
}

// load 8 bf16 (16B) fragment
__device__ __forceinline__ bf16x8 ldfrag(const unsigned short* p) {
    uint4 v = *(const uint4*)p;
    return __builtin_bit_cast(bf16x8, v);
}

__device__ __forceinline__ f32x4 mfma16(bf16x8 a, bf16x8 b, f32x4 c) {
    return __builtin_amdgcn_mfma_f32_16x16x32_bf16(a, b, c, 0, 0, 0);
}

// ---------------- kernel: pack mask int32 -> bitmask (1 bit/elem) ----------
__global__ __launch_bounds__(256) void mask_bits_kernel(
    const int* __restrict__ mask, unsigned long long* __restrict__ bits)
{
    size_t i = (size_t)blockIdx.x * 256 + threadIdx.x;
    int m = mask[i];
    unsigned long long b = __ballot(m != 0);
    if ((threadIdx.x & 63) == 0) bits[i >> 6] = b;
}

// ---------------- kernel: Wo fp32 -> bf16 ----------------------------------
__global__ __launch_bounds__(256) void wo_cvt_kernel(
    const float* __restrict__ Wo, unsigned short* __restrict__ Wob)
{
    size_t i = ((size_t)blockIdx.x * 256 + threadIdx.x) * 4;
    float4 v = *(const float4*)(Wo + i);
    u16x4 u;
    u[0] = f2bf(v.x); u[1] = f2bf(v.y); u[2] = f2bf(v.z); u[3] = f2bf(v.w);
    *(u16x4*)(Wob + i) = u;
}

// ---------------- kernel: QKV head projections via MFMA --------------------
// grid = 3 * HEADS * 64 : t3 selects tensor, h head, rt a 64-row tile.
// Y[t][e] = sum_d X[t][h*64+d] * W[e][d]
// Q,K stored [n][h][s][e] bf16 ; V stored transposed [n][h][e][s] bf16
__global__ __launch_bounds__(256) void proj_kernel(
    const float* __restrict__ qin, const float* __restrict__ kin, const float* __restrict__ vin,
    const float* __restrict__ Wq, const float* __restrict__ Wk, const float* __restrict__ Wv,
    unsigned short* __restrict__ Qb, unsigned short* __restrict__ Kb,
    unsigned short* __restrict__ Vt)
{
    int t3  = blockIdx.x >> 10;
    int rem = blockIdx.x & 1023;
    int h   = rem >> 6;
    int rt  = rem & 63;
    int wave = threadIdx.x >> 6, lane = threadIdx.x & 63;
    int quad = lane >> 4, l16 = lane & 15;

    const float* in = (t3 == 0) ? qin : ((t3 == 1) ? kin : vin);
    const float* W  = (t3 == 0) ? Wq  : ((t3 == 1) ? Wk  : Wv);

    int r0 = rt * 64 + wave * 16;   // global token row base for this wave

    // B fragments: W[e][d], e = sl*16 + l16, d = (0|32) + quad*8 + j
    bf16x8 bf0[4], bf1[4];
#pragma unroll
    for (int sl = 0; sl < 4; ++sl) {
        const float* wrow = W + (sl * 16 + l16) * 64;
        bf0[sl] = cvt8(wrow + quad * 8);
        bf1[sl] = cvt8(wrow + 32 + quad * 8);
    }
    // A fragments: X[row][h*64 + d]
    const float* xrow = in + (size_t)(r0 + l16) * ED + h * 64;
    bf16x8 af0 = cvt8(xrow + quad * 8);
    bf16x8 af1 = cvt8(xrow + 32 + quad * 8);

    f32x4 acc[4];
#pragma unroll
    for (int sl = 0; sl < 4; ++sl) {
        f32x4 c = {0.f, 0.f, 0.f, 0.f};
        c = mfma16(af0, bf0[sl], c);
        c = mfma16(af1, bf1[sl], c);
        acc[sl] = c;
    }

#pragma unroll
    for (int r = 0; r < 4; ++r) {
        int row = r0 + quad * 4 + r;         // token row
        int n = row >> 11, s = row & 2047;
        size_t qk_base = ((size_t)(n * HEADS + h) * SEQ + s) * HD;
#pragma unroll
        for (int sl = 0; sl < 4; ++sl) {
            int e = sl * 16 + l16;
            unsigned short v = f2bf(acc[sl][r]);
            if (t3 == 0)      Qb[qk_base + e] = v;
            else if (t3 == 1) Kb[qk_base + e] = v;
            else              Vt[((size_t)(n * HEADS + h) * HD + e) * SEQ + s] = v;
        }
    }
}

// ---------------- kernel: flash attention (no-max-softmax) -----------------
// grid = 2048 blocks of 128 threads (2 waves x 16 queries = 32 q / block)
// XCD-swizzled: each XCD owns 4 (n,h) pairs so its L2 caches 2 MB of K/V.
__global__ __launch_bounds__(128) void attn_kernel(
    const unsigned short* __restrict__ Qb, const unsigned short* __restrict__ Kb,
    const unsigned short* __restrict__ Vt, const unsigned long long* __restrict__ mb,
    unsigned short* __restrict__ Ab)
{
    __shared__ unsigned short pl[2][16 * 72];   // per-wave 16 x 72 (stride 72: 16B aligned)
    int wave = threadIdx.x >> 6, lane = threadIdx.x & 63;
    int quad = lane >> 4, l16 = lane & 15;

    // swizzle: blockIdx -> (xcd, j); each xcd gets 4 consecutive (n,h) pairs
    int b   = blockIdx.x;
    int xcd = b & 7;
    int j   = b >> 3;            // 0..255
    int nh  = xcd * 4 + (j >> 6);
    int qb  = j & 63;
    int n   = nh >> 4, h = nh & 15;
    int q0  = qb * 32 + wave * 16;

    size_t headoff = (size_t)(n * HEADS + h) * SEQ * HD;
    const unsigned short* qrow = Qb + headoff + (size_t)(q0 + l16) * HD;
    bf16x8 qf0 = ldfrag(qrow + quad * 8);
    bf16x8 qf1 = ldfrag(qrow + 32 + quad * 8);

    const unsigned short* kbase = Kb + headoff + (size_t)l16 * HD + quad * 8;
    const unsigned short* vbase = Vt + headoff + (size_t)l16 * SEQ + quad * 8;  // [64][SEQ]
    const unsigned long long* mrow = mb + (size_t)n * (SEQ * SEQ / 64)
                                        + (size_t)(q0 + quad * 4) * (SEQ / 64);
    unsigned short* plw = pl[wave];

    f32x4 o[4] = {{0,0,0,0},{0,0,0,0},{0,0,0,0},{0,0,0,0}};
    float lsum[4] = {0.f, 0.f, 0.f, 0.f};
    const float scale2 = 0.045084413f;   // (1/32) * log2(e)

    for (int kb = 0; kb < SEQ; kb += 64) {
        // ---- batched loads: 8 K frags + 8 V frags + 4 mask words -----------
        const unsigned short* kr = kbase + (size_t)kb * HD;
        bf16x8 kf[4][2];
#pragma unroll
        for (int g = 0; g < 4; ++g) {
            kf[g][0] = ldfrag(kr + (size_t)g * 16 * HD);
            kf[g][1] = ldfrag(kr + (size_t)g * 16 * HD + 32);
        }
        const unsigned short* vr = vbase + kb;
        bf16x8 vf[4][2];
#pragma unroll
        for (int sl = 0; sl < 4; ++sl) {
            vf[sl][0] = ldfrag(vr + (size_t)sl * 16 * SEQ);
            vf[sl][1] = ldfrag(vr + (size_t)sl * 16 * SEQ + 32);
        }
        unsigned long long m64[4];
#pragma unroll
        for (int r = 0; r < 4; ++r)
            m64[r] = mrow[(size_t)r * (SEQ / 64) + (kb >> 6)];

        // ---- QK^T: 4 C-tiles of 16x16 --------------------------------------
        f32x4 c[4];
#pragma unroll
        for (int g = 0; g < 4; ++g) {
            f32x4 cc = {0.f, 0.f, 0.f, 0.f};
            cc = mfma16(qf0, kf[g][0], cc);
            cc = mfma16(qf1, kf[g][1], cc);
            c[g] = cc;
        }

        // ---- mask + exp (no max-shift: |energy/32| < ~2) -------------------
#pragma unroll
        for (int r = 0; r < 4; ++r) {
            float rs = 0.f;
#pragma unroll
            for (int g = 0; g < 4; ++g) {
                float p = ((m64[r] >> (g * 16 + l16)) & 1ull)
                              ? __builtin_exp2f(c[g][r] * scale2) : 0.f;
                rs += p;
                plw[(quad * 4 + r) * 72 + g * 16 + l16] = f2bf(p);
            }
            lsum[r] += rs;
        }

        // ---- C-layout -> A-layout through per-wave LDS ---------------------
        bf16x8 pf0 = ldfrag(plw + l16 * 72 + quad * 8);
        bf16x8 pf1 = ldfrag(plw + l16 * 72 + 32 + quad * 8);
#pragma unroll
        for (int sl = 0; sl < 4; ++sl) {
            o[sl] = mfma16(pf0, vf[sl][0], o[sl]);
            o[sl] = mfma16(pf1, vf[sl][1], o[sl]);
        }
    }

    // reduce row sums across the 16 lanes of each quad
    float rinv[4];
#pragma unroll
    for (int r = 0; r < 4; ++r) {
        float s = lsum[r];
        s += __shfl_xor(s, 1);
        s += __shfl_xor(s, 2);
        s += __shfl_xor(s, 4);
        s += __shfl_xor(s, 8);
        rinv[r] = 1.0f / s;
    }
#pragma unroll
    for (int r = 0; r < 4; ++r) {
        int qrowi = q0 + quad * 4 + r;
        size_t obase = ((size_t)(n * SEQ + qrowi) * HEADS + h) * HD;
#pragma unroll
        for (int sl = 0; sl < 4; ++sl)
            Ab[obase + sl * 16 + l16] = f2bf(o[sl][r] * rinv[r]);
    }
}

// ---------------- kernel: out = Ab @ Wo^T + bo -----------------------------
// grid = (4096/64) * (1024/64) = 1024 ; block 256 (4 waves x 16 rows, 64 cols)
__global__ __launch_bounds__(256) void out_gemm_kernel(
    const unsigned short* __restrict__ Ab, const unsigned short* __restrict__ Wob,
    const float* __restrict__ bo, float* __restrict__ out)
{
    int wave = threadIdx.x >> 6, lane = threadIdx.x & 63;
    int quad = lane >> 4, l16 = lane & 15;
    int br = blockIdx.x >> 4, bc = blockIdx.x & 15;
    int rb = br * 64 + wave * 16;
    int cb = bc * 64;

    const unsigned short* arow = Ab + (size_t)(rb + l16) * ED + quad * 8;
    const unsigned short* wrow = Wob + (size_t)(cb + l16) * ED + quad * 8;

    f32x4 acc[4] = {{0,0,0,0},{0,0,0,0},{0,0,0,0},{0,0,0,0}};
    for (int f = 0; f < ED; f += 64) {
        bf16x8 af0 = ldfrag(arow + f);
        bf16x8 af1 = ldfrag(arow + f + 32);
        bf16x8 bf[4][2];
#pragma unroll
        for (int sl = 0; sl < 4; ++sl) {
            bf[sl][0] = ldfrag(wrow + (size_t)sl * 16 * ED + f);
            bf[sl][1] = ldfrag(wrow + (size_t)sl * 16 * ED + f + 32);
        }
#pragma unroll
        for (int sl = 0; sl < 4; ++sl) {
            acc[sl] = mfma16(af0, bf[sl][0], acc[sl]);
            acc[sl] = mfma16(af1, bf[sl][1], acc[sl]);
        }
    }
#pragma unroll
    for (int r = 0; r < 4; ++r) {
        int row = rb + quad * 4 + r;
#pragma unroll
        for (int sl = 0; sl < 4; ++sl) {
            int e = cb + sl * 16 + l16;
            out[(size_t)row * ED + e] = acc[sl][r] + bo[e];
        }
    }
}

// ---------------- launcher -------------------------------------------------
extern "C" void kernel_launch(void* const* d_in, const int* in_sizes, int n_in,
                              void* d_out, int out_size, void* d_ws, size_t ws_size,
                              hipStream_t stream)
{
    const float* values = (const float*)d_in[0];
    const float* keys   = (const float*)d_in[1];
    const float* query  = (const float*)d_in[2];
    const int*   mask   = (const int*)d_in[3];
    const float* Wv     = (const float*)d_in[4];
    const float* Wk     = (const float*)d_in[5];
    const float* Wq     = (const float*)d_in[6];
    const float* Wo     = (const float*)d_in[7];
    const float* bo     = (const float*)d_in[8];
    float* out = (float*)d_out;

    char* w = (char*)d_ws;
    unsigned short* Qb  = (unsigned short*)(w);              //  8 MB  [N][H][S][64] bf16
    unsigned short* Kb  = (unsigned short*)(w +  8388608);   //  8 MB  [N][H][S][64] bf16
    unsigned short* Vt  = (unsigned short*)(w + 16777216);   //  8 MB  [N][H][64][S] bf16
    unsigned short* Ab  = (unsigned short*)(w + 25165824);   //  8 MB  [N][S][H][64] bf16
    unsigned long long* Mb = (unsigned long long*)(w + 33554432); // 1 MB bitmask
    unsigned short* Wob = (unsigned short*)(w + 34603008);   //  2 MB  Wo bf16

    mask_bits_kernel<<<NB * SEQ * SEQ / 256, 256, 0, stream>>>(mask, Mb);
    wo_cvt_kernel<<<ED * ED / (256 * 4), 256, 0, stream>>>(Wo, Wob);
    proj_kernel<<<3 * HEADS * 64, 256, 0, stream>>>(query, keys, values, Wq, Wk, Wv, Qb, Kb, Vt);
    attn_kernel<<<2048, 128, 0, stream>>>(Qb, Kb, Vt, Mb, Ab);
    out_gemm_kernel<<<(NB * SEQ / 64) * (ED / 64), 256, 0, stream>>>(Ab, Wob, bo, out);
}

// Round 4
// 333.118 us; speedup vs baseline: 1.4400x; 1.4400x over previous
//
#include <hip/hip_runtime.h>
#include <hip/hip_bf16.h>

// Problem constants
#define NB 2
#define SEQ 2048
#define HEADS 16
#define HD 64
#define ED 1024

typedef __bf16 bf16x8 __attribute__((ext_vector_type(8)));
typedef float f32x4 __attribute__((ext_vector_type(4)));
typedef unsigned short u16x8 __attribute__((ext_vector_type(8)));
typedef unsigned short u16x4 __attribute__((ext_vector_type(4)));

__device__ __forceinline__ unsigned short f2bf(float f) {
    unsigned u = __builtin_bit_cast(unsigned, f);
    u += 0x7fffu + ((u >> 16) & 1u);   // RNE
    return (unsigned short)(u >> 16);
}

__device__ __forceinline__ bf16x8 cvt8(const float* __restrict__ p) {
    const float4* p4 = (const float4*)p;
    float4 a = p4[0], b = p4[1];
    u16x8 u;
    u[0] = f2bf(a.x); u[1] = f2bf(a.y); u[2] = f2bf(a.z); u[3] = f2bf(a.w);
    u[4] = f2bf(b.x); u[5] = f2bf(b.y); u[6] = f2bf(b.z); u[7] = f2bf(b.w);
    return __builtin_bit_cast(bf16x8, u);
}

__device__ __forceinline__ bf16x8 ldfrag(const void* p) {
    uint4 v = *(const uint4*)p;
    return __builtin_bit_cast(bf16x8, v);
}

__device__ __forceinline__ f32x4 mfma16(bf16x8 a, bf16x8 b, f32x4 c) {
    return __builtin_amdgcn_mfma_f32_16x16x32_bf16(a, b, c, 0, 0, 0);
}

#define GLOAD_LDS(gp, lp) \
    __builtin_amdgcn_global_load_lds( \
        (const __attribute__((address_space(1))) unsigned int*)(gp), \
        (__attribute__((address_space(3))) unsigned int*)(lp), 16, 0, 0)

// ---------------- kernel: pack mask int32 -> bitmask (1 bit/elem) ----------
__global__ __launch_bounds__(256) void mask_bits_kernel(
    const int* __restrict__ mask, unsigned long long* __restrict__ bits)
{
    size_t i = (size_t)blockIdx.x * 256 + threadIdx.x;
    int m = mask[i];
    unsigned long long b = __ballot(m != 0);
    if ((threadIdx.x & 63) == 0) bits[i >> 6] = b;
}

// ---------------- kernel: Wo fp32 -> bf16 ----------------------------------
__global__ __launch_bounds__(256) void wo_cvt_kernel(
    const float* __restrict__ Wo, unsigned short* __restrict__ Wob)
{
    size_t i = ((size_t)blockIdx.x * 256 + threadIdx.x) * 4;
    float4 v = *(const float4*)(Wo + i);
    u16x4 u;
    u[0] = f2bf(v.x); u[1] = f2bf(v.y); u[2] = f2bf(v.z); u[3] = f2bf(v.w);
    *(u16x4*)(Wob + i) = u;
}

// ---------------- kernel: QKV head projections via MFMA --------------------
// Q,K stored [n][h][s][64] bf16 ; V stored tiled [n][h][s/64][d][64] bf16
__global__ __launch_bounds__(256) void proj_kernel(
    const float* __restrict__ qin, const float* __restrict__ kin, const float* __restrict__ vin,
    const float* __restrict__ Wq, const float* __restrict__ Wk, const float* __restrict__ Wv,
    unsigned short* __restrict__ Qb, unsigned short* __restrict__ Kb,
    unsigned short* __restrict__ Vt)
{
    int t3  = blockIdx.x >> 10;
    int rem = blockIdx.x & 1023;
    int h   = rem >> 6;
    int rt  = rem & 63;
    int wave = threadIdx.x >> 6, lane = threadIdx.x & 63;
    int quad = lane >> 4, l16 = lane & 15;

    const float* in = (t3 == 0) ? qin : ((t3 == 1) ? kin : vin);
    const float* W  = (t3 == 0) ? Wq  : ((t3 == 1) ? Wk  : Wv);

    int r0 = rt * 64 + wave * 16;   // global token row base for this wave

    bf16x8 bf0[4], bf1[4];
#pragma unroll
    for (int sl = 0; sl < 4; ++sl) {
        const float* wrow = W + (sl * 16 + l16) * 64;
        bf0[sl] = cvt8(wrow + quad * 8);
        bf1[sl] = cvt8(wrow + 32 + quad * 8);
    }
    const float* xrow = in + (size_t)(r0 + l16) * ED + h * 64;
    bf16x8 af0 = cvt8(xrow + quad * 8);
    bf16x8 af1 = cvt8(xrow + 32 + quad * 8);

    f32x4 acc[4];
#pragma unroll
    for (int sl = 0; sl < 4; ++sl) {
        f32x4 c = {0.f, 0.f, 0.f, 0.f};
        c = mfma16(af0, bf0[sl], c);
        c = mfma16(af1, bf1[sl], c);
        acc[sl] = c;
    }

#pragma unroll
    for (int r = 0; r < 4; ++r) {
        int row = r0 + quad * 4 + r;         // token row
        int n = row >> 11, s = row & 2047;
        size_t nh = (size_t)(n * HEADS + h);
        size_t qk_base = (nh * SEQ + s) * HD;
#pragma unroll
        for (int sl = 0; sl < 4; ++sl) {
            int e = sl * 16 + l16;
            unsigned short v = f2bf(acc[sl][r]);
            if (t3 == 0)      Qb[qk_base + e] = v;
            else if (t3 == 1) Kb[qk_base + e] = v;
            else              Vt[((nh * 32 + (s >> 6)) * 64 + e) * 64 + (s & 63)] = v;
        }
    }
}

// ---------------- kernel: flash attention, LDS-staged K/V ------------------
// grid = 1024 blocks of 128 threads (2 waves x 32 queries = 64 q / block)
// K-tile [key][d] and V-tile [d][key] staged in LDS via global_load_lds with
// per-row rotation swizzle (slot (g+row)&7) -> bank-balanced ds_read_b128.
__global__ __launch_bounds__(128) void attn_kernel(
    const unsigned short* __restrict__ Qb, const unsigned short* __restrict__ Kb,
    const unsigned short* __restrict__ Vt2, const unsigned long long* __restrict__ mb,
    unsigned short* __restrict__ Ab)
{
    __shared__ __align__(16) char smem[8192 + 8192 + 4 * 2304];  // K, V, P(2 waves x 2 tiles)

    int tid = threadIdx.x;
    int wave = tid >> 6, lane = tid & 63;
    int quad = lane >> 4, l16 = lane & 15;

    int b  = blockIdx.x;
    int nh = b >> 5;
    int qb = b & 31;
    int n  = nh >> 4, h = nh & 15;
    int q0 = qb * 64 + wave * 32;          // this wave's 32 queries

    size_t headoff = (size_t)nh * SEQ * HD;
    // Q fragments: 2 q-subtiles of 16
    bf16x8 qf[2][2];
#pragma unroll
    for (int t = 0; t < 2; ++t) {
        const unsigned short* qrow = Qb + headoff + (size_t)(q0 + t * 16 + l16) * HD;
        qf[t][0] = ldfrag(qrow + quad * 8);
        qf[t][1] = ldfrag(qrow + 32 + quad * 8);
    }

    // staging: per-lane source offset (bytes) with rotation ((s - row)&7)
    int srow = lane >> 3, sslot = lane & 7;
    int stoff = srow * 128 + (((sslot - srow) & 7) * 16);

    // ds read address registers (bytes, loop-invariant)
    int rotA = ((quad + l16) & 7) * 16;
    int aK  = l16 * 128 + rotA;           // + kt*2048 imm ; ^64 -> d/key high half
    int aKx = aK ^ 64;
    int aV  = 8192 + l16 * 128 + rotA;    // + sl*2048 imm
    int aVx = aV ^ 64;
    char* pbase = smem + 16384 + wave * 2 * 2304;   // + t*2304
    // P write addr (bytes): (quad*4+r)*144 + kt*32 + l16*2 ; read: l16*144 + quad*16 (+64)

    const unsigned short* gK = Kb + headoff;                    // rows 128 B contiguous
    const unsigned short* gV = Vt2 + (size_t)nh * (32 * 4096);  // 8 KB tiles contiguous
    const unsigned long long* mbase = mb + (size_t)n * (SEQ * SEQ / 64)
                                         + (size_t)(q0 + quad * 4) * (SEQ / 64);

    f32x4 o[2][4] = {{{0,0,0,0},{0,0,0,0},{0,0,0,0},{0,0,0,0}},
                     {{0,0,0,0},{0,0,0,0},{0,0,0,0},{0,0,0,0}}};
    float lsum[2][4] = {{0,0,0,0},{0,0,0,0}};
    const float scale2 = 0.045084413f;   // (1/32) * log2(e)

    for (int kb = 0; kb < SEQ; kb += 64) {
        __syncthreads();   // all waves done reading previous tile
        // ---- stage K tile (8 KB) + V tile (8 KB): 4+4 chunks per wave ------
        const char* srcK = (const char*)(gK + (size_t)kb * 64) + stoff;
        const char* srcV = (const char*)(gV + (size_t)(kb >> 6) * 4096) + stoff;
#pragma unroll
        for (int i = 0; i < 4; ++i) {
            int c = wave * 4 + i;
            GLOAD_LDS(srcK + c * 1024, smem + c * 1024);
            GLOAD_LDS(srcV + c * 1024, smem + 8192 + c * 1024);
        }
        // mask words (independent, L2-hot)
        unsigned long long m64[2][4];
#pragma unroll
        for (int t = 0; t < 2; ++t)
#pragma unroll
            for (int r = 0; r < 4; ++r)
                m64[t][r] = mbase[(size_t)(t * 16 + r) * (SEQ / 64) + (kb >> 6)] >> l16;
        __syncthreads();   // tile visible (vmcnt(0) drained by barrier)

        // ---- K fragments ---------------------------------------------------
        bf16x8 kf[4][2];
#pragma unroll
        for (int kt = 0; kt < 4; ++kt) {
            kf[kt][0] = ldfrag(smem + aK  + kt * 2048);
            kf[kt][1] = ldfrag(smem + aKx + kt * 2048);
        }
        // ---- per q-subtile: QK^T, mask+exp, P to LDS -----------------------
#pragma unroll
        for (int t = 0; t < 2; ++t) {
            f32x4 c[4];
#pragma unroll
            for (int kt = 0; kt < 4; ++kt) {
                f32x4 cc = {0.f, 0.f, 0.f, 0.f};
                cc = mfma16(qf[t][0], kf[kt][0], cc);
                cc = mfma16(qf[t][1], kf[kt][1], cc);
                c[kt] = cc;
            }
            char* pw = pbase + t * 2304 + quad * 576 + l16 * 2;
#pragma unroll
            for (int r = 0; r < 4; ++r) {
                unsigned long long m = m64[t][r];
                float rs = 0.f;
#pragma unroll
                for (int kt = 0; kt < 4; ++kt) {
                    float p = ((m >> (kt * 16)) & 1ull)
                                  ? __builtin_exp2f(c[kt][r] * scale2) : 0.f;
                    rs += p;
                    *(unsigned short*)(pw + r * 144 + kt * 32) = f2bf(p);
                }
                lsum[t][r] += rs;
            }
        }
        // ---- PV: P (A-layout via LDS) x V ----------------------------------
#pragma unroll
        for (int t = 0; t < 2; ++t) {
            char* pr = pbase + t * 2304 + l16 * 144 + quad * 16;
            bf16x8 pf0 = ldfrag(pr);
            bf16x8 pf1 = ldfrag(pr + 64);
#pragma unroll
            for (int sl = 0; sl < 4; ++sl) {
                o[t][sl] = mfma16(pf0, ldfrag(smem + aV  + sl * 2048), o[t][sl]);
                o[t][sl] = mfma16(pf1, ldfrag(smem + aVx + sl * 2048), o[t][sl]);
            }
        }
    }

    // ---- epilogue: normalize and store -------------------------------------
#pragma unroll
    for (int t = 0; t < 2; ++t) {
        float rinv[4];
#pragma unroll
        for (int r = 0; r < 4; ++r) {
            float s = lsum[t][r];
            s += __shfl_xor(s, 1);
            s += __shfl_xor(s, 2);
            s += __shfl_xor(s, 4);
            s += __shfl_xor(s, 8);
            rinv[r] = 1.0f / s;
        }
#pragma unroll
        for (int r = 0; r < 4; ++r) {
            int qrowi = q0 + t * 16 + quad * 4 + r;
            size_t obase = ((size_t)(n * SEQ + qrowi) * HEADS + h) * HD;
#pragma unroll
            for (int sl = 0; sl < 4; ++sl)
                Ab[obase + sl * 16 + l16] = f2bf(o[t][sl][r] * rinv[r]);
        }
    }
}

// ---------------- kernel: out = Ab @ Wo^T + bo -----------------------------
__global__ __launch_bounds__(256) void out_gemm_kernel(
    const unsigned short* __restrict__ Ab, const unsigned short* __restrict__ Wob,
    const float* __restrict__ bo, float* __restrict__ out)
{
    int wave = threadIdx.x >> 6, lane = threadIdx.x & 63;
    int quad = lane >> 4, l16 = lane & 15;
    int br = blockIdx.x >> 4, bc = blockIdx.x & 15;
    int rb = br * 64 + wave * 16;
    int cb = bc * 64;

    const unsigned short* arow = Ab + (size_t)(rb + l16) * ED + quad * 8;
    const unsigned short* wrow = Wob + (size_t)(cb + l16) * ED + quad * 8;

    f32x4 acc[4] = {{0,0,0,0},{0,0,0,0},{0,0,0,0},{0,0,0,0}};
    for (int f = 0; f < ED; f += 64) {
        bf16x8 af0 = ldfrag(arow + f);
        bf16x8 af1 = ldfrag(arow + f + 32);
        bf16x8 bf[4][2];
#pragma unroll
        for (int sl = 0; sl < 4; ++sl) {
            bf[sl][0] = ldfrag(wrow + (size_t)sl * 16 * ED + f);
            bf[sl][1] = ldfrag(wrow + (size_t)sl * 16 * ED + f + 32);
        }
#pragma unroll
        for (int sl = 0; sl < 4; ++sl) {
            acc[sl] = mfma16(af0, bf[sl][0], acc[sl]);
            acc[sl] = mfma16(af1, bf[sl][1], acc[sl]);
        }
    }
#pragma unroll
    for (int r = 0; r < 4; ++r) {
        int row = rb + quad * 4 + r;
#pragma unroll
        for (int sl = 0; sl < 4; ++sl) {
            int e = cb + sl * 16 + l16;
            out[(size_t)row * ED + e] = acc[sl][r] + bo[e];
        }
    }
}

// ---------------- launcher -------------------------------------------------
extern "C" void kernel_launch(void* const* d_in, const int* in_sizes, int n_in,
                              void* d_out, int out_size, void* d_ws, size_t ws_size,
                              hipStream_t stream)
{
    const float* values = (const float*)d_in[0];
    const float* keys   = (const float*)d_in[1];
    const float* query  = (const float*)d_in[2];
    const int*   mask   = (const int*)d_in[3];
    const float* Wv     = (const float*)d_in[4];
    const float* Wk     = (const float*)d_in[5];
    const float* Wq     = (const float*)d_in[6];
    const float* Wo     = (const float*)d_in[7];
    const float* bo     = (const float*)d_in[8];
    float* out = (float*)d_out;

    char* w = (char*)d_ws;
    unsigned short* Qb  = (unsigned short*)(w);              //  8 MB  [N][H][S][64] bf16
    unsigned short* Kb  = (unsigned short*)(w +  8388608);   //  8 MB  [N][H][S][64] bf16
    unsigned short* Vt  = (unsigned short*)(w + 16777216);   //  8 MB  [N][H][S/64][64][64] bf16
    unsigned short* Ab  = (unsigned short*)(w + 25165824);   //  8 MB  [N][S][H][64] bf16
    unsigned long long* Mb = (unsigned long long*)(w + 33554432); // 1 MB bitmask
    unsigned short* Wob = (unsigned short*)(w + 34603008);   //  2 MB  Wo bf16

    mask_bits_kernel<<<NB * SEQ * SEQ / 256, 256, 0, stream>>>(mask, Mb);
    wo_cvt_kernel<<<ED * ED / (256 * 4), 256, 0, stream>>>(Wo, Wob);
    proj_kernel<<<3 * HEADS * 64, 256, 0, stream>>>(query, keys, values, Wq, Wk, Wv, Qb, Kb, Vt);
    attn_kernel<<<1024, 128, 0, stream>>>(Qb, Kb, Vt, Mb, Ab);
    out_gemm_kernel<<<(NB * SEQ / 64) * (ED / 64), 256, 0, stream>>>(Ab, Wob, bo, out);
}

// Round 5
// 260.128 us; speedup vs baseline: 1.8441x; 1.2806x over previous
//
#include <hip/hip_runtime.h>
#include <hip/hip_bf16.h>

// Problem constants
#define NB 2
#define SEQ 2048
#define HEADS 16
#define HD 64
#define ED 1024

typedef __bf16 bf16x8 __attribute__((ext_vector_type(8)));
typedef float f32x4 __attribute__((ext_vector_type(4)));
typedef unsigned short u16x8 __attribute__((ext_vector_type(8)));
typedef unsigned short u16x4 __attribute__((ext_vector_type(4)));

__device__ __forceinline__ unsigned short f2bf(float f) {
    unsigned u = __builtin_bit_cast(unsigned, f);
    u += 0x7fffu + ((u >> 16) & 1u);   // RNE
    return (unsigned short)(u >> 16);
}

__device__ __forceinline__ bf16x8 cvt8(const float* __restrict__ p) {
    const float4* p4 = (const float4*)p;
    float4 a = p4[0], b = p4[1];
    u16x8 u;
    u[0] = f2bf(a.x); u[1] = f2bf(a.y); u[2] = f2bf(a.z); u[3] = f2bf(a.w);
    u[4] = f2bf(b.x); u[5] = f2bf(b.y); u[6] = f2bf(b.z); u[7] = f2bf(b.w);
    return __builtin_bit_cast(bf16x8, u);
}

__device__ __forceinline__ bf16x8 ldfrag(const void* p) {
    uint4 v = *(const uint4*)p;
    return __builtin_bit_cast(bf16x8, v);
}

__device__ __forceinline__ f32x4 mfma16(bf16x8 a, bf16x8 b, f32x4 c) {
    return __builtin_amdgcn_mfma_f32_16x16x32_bf16(a, b, c, 0, 0, 0);
}

#define GLOAD_LDS(gp, lp) \
    __builtin_amdgcn_global_load_lds( \
        (const __attribute__((address_space(1))) unsigned int*)(gp), \
        (__attribute__((address_space(3))) unsigned int*)(lp), 16, 0, 0)

// softmax scale folded into Q at projection: (1/sqrt(1024)) * log2(e)
#define QSCALE 0.04508422f

// ---------------- kernel: pack mask int32 -> bitmask (1 bit/elem) ----------
__global__ __launch_bounds__(256) void mask_bits_kernel(
    const int* __restrict__ mask, unsigned long long* __restrict__ bits)
{
    size_t i = (size_t)blockIdx.x * 256 + threadIdx.x;
    int m = mask[i];
    unsigned long long b = __ballot(m != 0);
    if ((threadIdx.x & 63) == 0) bits[i >> 6] = b;
}

// ---------------- kernel: Wo fp32 -> bf16 ----------------------------------
__global__ __launch_bounds__(256) void wo_cvt_kernel(
    const float* __restrict__ Wo, unsigned short* __restrict__ Wob)
{
    size_t i = ((size_t)blockIdx.x * 256 + threadIdx.x) * 4;
    float4 v = *(const float4*)(Wo + i);
    u16x4 u;
    u[0] = f2bf(v.x); u[1] = f2bf(v.y); u[2] = f2bf(v.z); u[3] = f2bf(v.w);
    *(u16x4*)(Wob + i) = u;
}

// ---------------- kernel: QKV head projections via MFMA --------------------
// Q,K stored [n][h][s][64] bf16 (Q pre-scaled by QSCALE);
// V stored tiled [n][h][s/64][d][64] bf16.
// Epilogue goes through an LDS transpose so all global stores are 1KB-
// contiguous dwordx4 (the 2B/128B-stride scatter was the old bottleneck).
__global__ __launch_bounds__(256) void proj_kernel(
    const float* __restrict__ qin, const float* __restrict__ kin, const float* __restrict__ vin,
    const float* __restrict__ Wq, const float* __restrict__ Wk, const float* __restrict__ Wv,
    unsigned short* __restrict__ Qb, unsigned short* __restrict__ Kb,
    unsigned short* __restrict__ Vt)
{
    __shared__ __align__(16) char tile[64 * 144];   // 64 rows x 144B (128B data + pad)

    int t3  = blockIdx.x >> 10;
    int rem = blockIdx.x & 1023;
    int h   = rem >> 6;
    int rt  = rem & 63;
    int wave = threadIdx.x >> 6, lane = threadIdx.x & 63;
    int quad = lane >> 4, l16 = lane & 15;

    const float* in = (t3 == 0) ? qin : ((t3 == 1) ? kin : vin);
    const float* W  = (t3 == 0) ? Wq  : ((t3 == 1) ? Wk  : Wv);

    int r0 = rt * 64 + wave * 16;   // global token row base for this wave

    bf16x8 bf0[4], bf1[4];
#pragma unroll
    for (int sl = 0; sl < 4; ++sl) {
        const float* wrow = W + (sl * 16 + l16) * 64;
        bf0[sl] = cvt8(wrow + quad * 8);
        bf1[sl] = cvt8(wrow + 32 + quad * 8);
    }
    const float* xrow = in + (size_t)(r0 + l16) * ED + h * 64;
    bf16x8 af0 = cvt8(xrow + quad * 8);
    bf16x8 af1 = cvt8(xrow + 32 + quad * 8);

    f32x4 acc[4];
#pragma unroll
    for (int sl = 0; sl < 4; ++sl) {
        f32x4 c = {0.f, 0.f, 0.f, 0.f};
        c = mfma16(af0, bf0[sl], c);
        c = mfma16(af1, bf1[sl], c);
        acc[sl] = c;
    }
    float sc = (t3 == 0) ? QSCALE : 1.0f;

    size_t nh = (size_t)((r0 >> 11) * HEADS + h);   // 64-row tile never straddles n
    int rl = lane >> 3, cl = lane & 7;              // readback row-in-group / 16B slot

    if (t3 != 2) {
        // ---- Q/K: LDS tile [s_local][e], wave-private rows, no barrier -----
#pragma unroll
        for (int r = 0; r < 4; ++r) {
            int srow = wave * 16 + quad * 4 + r;
#pragma unroll
            for (int sl = 0; sl < 4; ++sl)
                *(unsigned short*)(tile + srow * 144 + (sl * 16 + l16) * 2) =
                    f2bf(acc[sl][r] * sc);
        }
        unsigned short* dst = (t3 == 0) ? Qb : Kb;
        int s0 = (r0 & 2047);                        // this wave's first token row
#pragma unroll
        for (int g = 0; g < 2; ++g) {
            int lrow = wave * 16 + g * 8 + rl;
            uint4 v = *(const uint4*)(tile + lrow * 144 + cl * 16);
            *(uint4*)(dst + (nh * SEQ + (s0 & ~15) + g * 8 + rl) * HD + cl * 8) = v;
        }
    } else {
        // ---- V: LDS tile [e][s_local] (transpose), barrier across waves ----
#pragma unroll
        for (int r = 0; r < 4; ++r) {
            int srow = wave * 16 + quad * 4 + r;
#pragma unroll
            for (int sl = 0; sl < 4; ++sl)
                *(unsigned short*)(tile + (sl * 16 + l16) * 144 + srow * 2) =
                    f2bf(acc[sl][r]);
        }
        __syncthreads();
        int s_tile = rt & 31;
#pragma unroll
        for (int g = 0; g < 2; ++g) {
            int erow = wave * 16 + g * 8 + rl;
            uint4 v = *(const uint4*)(tile + erow * 144 + cl * 16);
            *(uint4*)(Vt + ((nh * 32 + s_tile) * 64 + erow) * 64 + cl * 8) = v;
        }
    }
}

// ---------------- kernel: flash attention, LDS-staged K/V ------------------
// 256 threads = 4 waves x 32 queries = 128 q / block.
// SPLIT=1: grid 1024 (16 qb x 32 nh x 2 k-halves), partial O (f32) + lsum out.
// SPLIT=0: grid 512, full K sweep, normalized bf16 out.
template <int SPLIT>
__global__ __launch_bounds__(256) void attn_kernel(
    const unsigned short* __restrict__ Qb, const unsigned short* __restrict__ Kb,
    const unsigned short* __restrict__ Vt2, const unsigned long long* __restrict__ mb,
    unsigned short* __restrict__ Ab, float* __restrict__ Of, float* __restrict__ Ls)
{
    __shared__ __align__(16) char smem[8192 + 8192 + 4 * 4608];  // K, V, P per wave

    int tid = threadIdx.x;
    int wave = tid >> 6, lane = tid & 63;
    int quad = lane >> 4, l16 = lane & 15;

    // XCD swizzle: 4 consecutive nh per XCD -> K/V resident in its L2
    int b   = blockIdx.x;
    int xcd = b & 7;
    int j   = b >> 3;
    int nh, qb, half;
    if (SPLIT) { nh = xcd * 4 + (j >> 5); int r = j & 31; qb = r >> 1; half = r & 1; }
    else       { nh = xcd * 4 + (j >> 4); qb = j & 15; half = 0; }
    int n = nh >> 4, h = nh & 15;
    int q0 = qb * 128 + wave * 32;          // this wave's 32 queries

    size_t headoff = (size_t)nh * SEQ * HD;
    bf16x8 qf[2][2];
#pragma unroll
    for (int t = 0; t < 2; ++t) {
        const unsigned short* qrow = Qb + headoff + (size_t)(q0 + t * 16 + l16) * HD;
        qf[t][0] = ldfrag(qrow + quad * 8);
        qf[t][1] = ldfrag(qrow + 32 + quad * 8);
    }

    // staging: per-lane source offset (bytes) with rotation ((slot - row)&7)
    int srow = lane >> 3, sslot = lane & 7;
    int stoff = srow * 128 + (((sslot - srow) & 7) * 16);

    // ds read address registers (bytes, loop-invariant)
    int rotA = ((quad + l16) & 7) * 16;
    int aK  = l16 * 128 + rotA;           // + kt*2048 imm ; ^64 -> high half
    int aKx = aK ^ 64;
    int aV  = 8192 + l16 * 128 + rotA;    // + sl*2048 imm
    int aVx = aV ^ 64;
    char* pbase = smem + 16384 + wave * 4608;   // + t*2304

    const unsigned short* gK = Kb + headoff;
    const unsigned short* gV = Vt2 + (size_t)nh * (32 * 4096);
    const unsigned long long* mbase = mb + (size_t)n * (SEQ * SEQ / 64)
                                         + (size_t)(q0 + quad * 4) * (SEQ / 64);

    f32x4 o[2][4] = {{{0,0,0,0},{0,0,0,0},{0,0,0,0},{0,0,0,0}},
                     {{0,0,0,0},{0,0,0,0},{0,0,0,0},{0,0,0,0}}};
    float lsum[2][4] = {{0,0,0,0},{0,0,0,0}};

    int kb0   = SPLIT ? half * (SEQ / 2) : 0;
    int kbend = SPLIT ? kb0 + (SEQ / 2) : SEQ;

    for (int kb = kb0; kb < kbend; kb += 64) {
        __syncthreads();   // all waves done reading previous tile
        // ---- stage K tile (8 KB) + V tile (8 KB): 4 chunks per wave --------
        const char* srcK = (const char*)(gK + (size_t)kb * 64) + stoff;
        const char* srcV = (const char*)(gV + (size_t)(kb >> 6) * 4096) + stoff;
#pragma unroll
        for (int i = 0; i < 4; ++i) {
            int c = wave * 4 + i;            // 0..15 (wave-uniform branch)
            if (c < 8) GLOAD_LDS(srcK + c * 1024, smem + c * 1024);
            else       GLOAD_LDS(srcV + (c - 8) * 1024, smem + 8192 + (c - 8) * 1024);
        }
        // mask words (independent, L2-hot), pre-shifted by l16
        unsigned long long m64[2][4];
#pragma unroll
        for (int t = 0; t < 2; ++t)
#pragma unroll
            for (int r = 0; r < 4; ++r)
                m64[t][r] = mbase[(size_t)(t * 16 + r) * (SEQ / 64) + (kb >> 6)] >> l16;
        __syncthreads();   // tile visible

        // ---- K fragments ---------------------------------------------------
        bf16x8 kf[4][2];
#pragma unroll
        for (int kt = 0; kt < 4; ++kt) {
            kf[kt][0] = ldfrag(smem + aK  + kt * 2048);
            kf[kt][1] = ldfrag(smem + aKx + kt * 2048);
        }
        // ---- per q-subtile: QK^T, mask+exp, P to LDS -----------------------
#pragma unroll
        for (int t = 0; t < 2; ++t) {
            f32x4 c[4];
#pragma unroll
            for (int kt = 0; kt < 4; ++kt) {
                f32x4 cc = {0.f, 0.f, 0.f, 0.f};
                cc = mfma16(qf[t][0], kf[kt][0], cc);
                cc = mfma16(qf[t][1], kf[kt][1], cc);
                c[kt] = cc;
            }
            char* pw = pbase + t * 2304 + quad * 576 + l16 * 2;
#pragma unroll
            for (int r = 0; r < 4; ++r) {
                unsigned mlo = (unsigned)m64[t][r];
                unsigned mhi = (unsigned)(m64[t][r] >> 32);
                // scores pre-scaled via Q; masked -> exact 0
                float p0 = (mlo & 1u)       ? __builtin_exp2f(c[0][r]) : 0.f;
                float p1 = (mlo & 0x10000u) ? __builtin_exp2f(c[1][r]) : 0.f;
                float p2 = (mhi & 1u)       ? __builtin_exp2f(c[2][r]) : 0.f;
                float p3 = (mhi & 0x10000u) ? __builtin_exp2f(c[3][r]) : 0.f;
                lsum[t][r] += (p0 + p1) + (p2 + p3);
                // round-half-up bf16 (2 ops/elem)
                *(unsigned short*)(pw + r * 144)      = (unsigned short)((__builtin_bit_cast(unsigned, p0) + 0x8000u) >> 16);
                *(unsigned short*)(pw + r * 144 + 32) = (unsigned short)((__builtin_bit_cast(unsigned, p1) + 0x8000u) >> 16);
                *(unsigned short*)(pw + r * 144 + 64) = (unsigned short)((__builtin_bit_cast(unsigned, p2) + 0x8000u) >> 16);
                *(unsigned short*)(pw + r * 144 + 96) = (unsigned short)((__builtin_bit_cast(unsigned, p3) + 0x8000u) >> 16);
            }
        }
        // ---- PV: P (A-layout via LDS) x V ----------------------------------
#pragma unroll
        for (int t = 0; t < 2; ++t) {
            char* pr = pbase + t * 2304 + l16 * 144 + quad * 16;
            bf16x8 pf0 = ldfrag(pr);
            bf16x8 pf1 = ldfrag(pr + 64);
#pragma unroll
            for (int sl = 0; sl < 4; ++sl) {
                o[t][sl] = mfma16(pf0, ldfrag(smem + aV  + sl * 2048), o[t][sl]);
                o[t][sl] = mfma16(pf1, ldfrag(smem + aVx + sl * 2048), o[t][sl]);
            }
        }
    }

    // ---- epilogue ----------------------------------------------------------
#pragma unroll
    for (int t = 0; t < 2; ++t) {
#pragma unroll
        for (int r = 0; r < 4; ++r) {
            float s = lsum[t][r];
            s += __shfl_xor(s, 1);
            s += __shfl_xor(s, 2);
            s += __shfl_xor(s, 4);
            s += __shfl_xor(s, 8);
            int qrowi = q0 + t * 16 + quad * 4 + r;
            if (SPLIT) {
                size_t qg = (size_t)nh * SEQ + qrowi;
                if (l16 == 0) Ls[(size_t)half * 65536 + qg] = s;
                float* op = Of + ((size_t)half * 65536 + qg) * 64;
#pragma unroll
                for (int sl = 0; sl < 4; ++sl)
                    op[sl * 16 + l16] = o[t][sl][r];
            } else {
                float rinv = 1.0f / s;
                size_t obase = ((size_t)(n * SEQ + qrowi) * HEADS + h) * HD;
#pragma unroll
                for (int sl = 0; sl < 4; ++sl)
                    Ab[obase + sl * 16 + l16] = f2bf(o[t][sl][r] * rinv);
            }
        }
    }
}

// ---------------- kernel: combine K-split halves ---------------------------
// Ab[(n*S+s)*H+h][d] = (O0+O1)/(l0+l1)
__global__ __launch_bounds__(256) void combine_kernel(
    const float* __restrict__ Of, const float* __restrict__ Ls,
    unsigned short* __restrict__ Ab)
{
    int idx = blockIdx.x * 256 + threadIdx.x;     // 1M threads, 4 floats each
    int q  = idx >> 4;                            // qglobal = nh*2048 + s
    int d0 = (idx & 15) * 4;
    const float4 o0 = *(const float4*)(Of + (size_t)q * 64 + d0);
    const float4 o1 = *(const float4*)(Of + 4194304 + (size_t)q * 64 + d0);
    float rl = 1.0f / (Ls[q] + Ls[65536 + q]);
    int n = q >> 15, h = (q >> 11) & 15, s = q & 2047;
    size_t ab = (((size_t)(n * SEQ + s)) * HEADS + h) * HD + d0;
    u16x4 u;
    u[0] = f2bf((o0.x + o1.x) * rl);
    u[1] = f2bf((o0.y + o1.y) * rl);
    u[2] = f2bf((o0.z + o1.z) * rl);
    u[3] = f2bf((o0.w + o1.w) * rl);
    *(u16x4*)(Ab + ab) = u;
}

// ---------------- kernel: out = Ab @ Wo^T + bo (m97-style) -----------------
// grid 256 = 32 row-tiles x 8 col-tiles of 128x128; 4 waves, each 64x64.
__global__ __launch_bounds__(256) void out_gemm_kernel(
    const unsigned short* __restrict__ Ab, const unsigned short* __restrict__ Wob,
    const float* __restrict__ bo, float* __restrict__ out)
{
    __shared__ __align__(16) char lds[32768];    // At 16KB + Bt 16KB (BK=64)

    int wave = threadIdx.x >> 6, lane = threadIdx.x & 63;
    int quad = lane >> 4, l16 = lane & 15;
    int rt = blockIdx.x >> 3, ct = blockIdx.x & 7;
    int wr = wave >> 1, wc = wave & 1;

    int srow = lane >> 3, sslot = lane & 7;
    int stoff = srow * 2048 + (((sslot - srow) & 7) * 16);
    const char* gA = (const char*)Ab  + (size_t)rt * 128 * 2048 + stoff;
    const char* gB = (const char*)Wob + (size_t)ct * 128 * 2048 + stoff;

    int aA[4], aB[4];
#pragma unroll
    for (int i = 0; i < 4; ++i) {
        int rowA = wr * 64 + i * 16 + l16;
        aA[i] = rowA * 128 + (((quad + rowA) & 7) * 16);
        int rowB = wc * 64 + i * 16 + l16;
        aB[i] = 16384 + rowB * 128 + (((quad + rowB) & 7) * 16);
    }

    f32x4 acc[4][4] = {};
    for (int f = 0; f < ED; f += 64) {
        __syncthreads();
#pragma unroll
        for (int i = 0; i < 4; ++i) {
            int c = wave * 4 + i;                     // 16 chunks of 8 rows
            GLOAD_LDS(gA + (size_t)c * 16384 + f * 2, lds + c * 1024);
            GLOAD_LDS(gB + (size_t)c * 16384 + f * 2, lds + 16384 + c * 1024);
        }
        __syncthreads();
#pragma unroll
        for (int kk = 0; kk < 2; ++kk) {
            int x = kk * 64;
            bf16x8 af[4], bfr[4];
#pragma unroll
            for (int i = 0; i < 4; ++i)  af[i]  = ldfrag(lds + (aA[i] ^ x));
#pragma unroll
            for (int sl = 0; sl < 4; ++sl) bfr[sl] = ldfrag(lds + (aB[sl] ^ x));
#pragma unroll
            for (int i = 0; i < 4; ++i)
#pragma unroll
                for (int sl = 0; sl < 4; ++sl)
                    acc[i][sl] = mfma16(af[i], bfr[sl], acc[i][sl]);
        }
    }

    float bv[4];
#pragma unroll
    for (int sl = 0; sl < 4; ++sl)
        bv[sl] = bo[ct * 128 + wc * 64 + sl * 16 + l16];
#pragma unroll
    for (int i = 0; i < 4; ++i)
#pragma unroll
        for (int r = 0; r < 4; ++r) {
            int row = rt * 128 + wr * 64 + i * 16 + quad * 4 + r;
#pragma unroll
            for (int sl = 0; sl < 4; ++sl) {
                int e = ct * 128 + wc * 64 + sl * 16 + l16;
                out[(size_t)row * ED + e] = acc[i][sl][r] + bv[sl];
            }
        }
}

// ---------------- launcher -------------------------------------------------
extern "C" void kernel_launch(void* const* d_in, const int* in_sizes, int n_in,
                              void* d_out, int out_size, void* d_ws, size_t ws_size,
                              hipStream_t stream)
{
    const float* values = (const float*)d_in[0];
    const float* keys   = (const float*)d_in[1];
    const float* query  = (const float*)d_in[2];
    const int*   mask   = (const int*)d_in[3];
    const float* Wv     = (const float*)d_in[4];
    const float* Wk     = (const float*)d_in[5];
    const float* Wq     = (const float*)d_in[6];
    const float* Wo     = (const float*)d_in[7];
    const float* bo     = (const float*)d_in[8];
    float* out = (float*)d_out;

    char* w = (char*)d_ws;
    unsigned short* Qb  = (unsigned short*)(w);              //  8 MB
    unsigned short* Kb  = (unsigned short*)(w +  8388608);   //  8 MB
    unsigned short* Vt  = (unsigned short*)(w + 16777216);   //  8 MB tiled V
    unsigned short* Ab  = (unsigned short*)(w + 25165824);   //  8 MB
    unsigned long long* Mb = (unsigned long long*)(w + 33554432); // 1 MB
    unsigned short* Wob = (unsigned short*)(w + 34603008);   //  2 MB
    float* Of = (float*)(w + 36700160);                      // 33.5 MB (split)
    float* Ls = (float*)(w + 70254592);                      // 0.5 MB  (split)

    bool split = ws_size >= 70778880ULL;

    mask_bits_kernel<<<NB * SEQ * SEQ / 256, 256, 0, stream>>>(mask, Mb);
    wo_cvt_kernel<<<ED * ED / (256 * 4), 256, 0, stream>>>(Wo, Wob);
    proj_kernel<<<3 * HEADS * 64, 256, 0, stream>>>(query, keys, values, Wq, Wk, Wv, Qb, Kb, Vt);
    if (split) {
        attn_kernel<1><<<1024, 256, 0, stream>>>(Qb, Kb, Vt, Mb, Ab, Of, Ls);
        combine_kernel<<<4096, 256, 0, stream>>>(Of, Ls, Ab);
    } else {
        attn_kernel<0><<<512, 256, 0, stream>>>(Qb, Kb, Vt, Mb, Ab, Of, Ls);
    }
    out_gemm_kernel<<<256, 256, 0, stream>>>(Ab, Wob, bo, out);
}

// Round 6
// 258.233 us; speedup vs baseline: 1.8576x; 1.0073x over previous
//
#include <hip/hip_runtime.h>
#include <hip/hip_bf16.h>

// Problem constants
#define NB 2
#define SEQ 2048
#define HEADS 16
#define HD 64
#define ED 1024

typedef __bf16 bf16x8 __attribute__((ext_vector_type(8)));
typedef float f32x4 __attribute__((ext_vector_type(4)));
typedef unsigned short u16x8 __attribute__((ext_vector_type(8)));
typedef unsigned short u16x4 __attribute__((ext_vector_type(4)));

__device__ __forceinline__ unsigned short f2bf(float f) {
    unsigned u = __builtin_bit_cast(unsigned, f);
    u += 0x7fffu + ((u >> 16) & 1u);   // RNE
    return (unsigned short)(u >> 16);
}

__device__ __forceinline__ bf16x8 cvt8(const float* __restrict__ p) {
    const float4* p4 = (const float4*)p;
    float4 a = p4[0], b = p4[1];
    u16x8 u;
    u[0] = f2bf(a.x); u[1] = f2bf(a.y); u[2] = f2bf(a.z); u[3] = f2bf(a.w);
    u[4] = f2bf(b.x); u[5] = f2bf(b.y); u[6] = f2bf(b.z); u[7] = f2bf(b.w);
    return __builtin_bit_cast(bf16x8, u);
}

__device__ __forceinline__ bf16x8 ldfrag(const void* p) {
    uint4 v = *(const uint4*)p;
    return __builtin_bit_cast(bf16x8, v);
}

__device__ __forceinline__ f32x4 mfma16(bf16x8 a, bf16x8 b, f32x4 c) {
    return __builtin_amdgcn_mfma_f32_16x16x32_bf16(a, b, c, 0, 0, 0);
}

// pack two positive f32 into bf16 pair (round-half-up), lo in low half
__device__ __forceinline__ unsigned packbf(float lo, float hi) {
    unsigned a = __builtin_bit_cast(unsigned, lo) + 0x8000u;
    unsigned b = __builtin_bit_cast(unsigned, hi) + 0x8000u;
    return (b & 0xFFFF0000u) | (a >> 16);
}

#define GLOAD_LDS(gp, lp) \
    __builtin_amdgcn_global_load_lds( \
        (const __attribute__((address_space(1))) unsigned int*)(gp), \
        (__attribute__((address_space(3))) unsigned int*)(lp), 16, 0, 0)

// softmax scale folded into Q at projection: (1/sqrt(1024)) * log2(e)
#define QSCALE 0.04508422f

// ---------------- kernel: pack mask int32 -> bitmask (1 bit/elem) ----------
__global__ __launch_bounds__(256) void mask_bits_kernel(
    const int* __restrict__ mask, unsigned long long* __restrict__ bits)
{
    size_t i = (size_t)blockIdx.x * 256 + threadIdx.x;
    int m = mask[i];
    unsigned long long b = __ballot(m != 0);
    if ((threadIdx.x & 63) == 0) bits[i >> 6] = b;
}

// ---------------- kernel: Wo fp32 -> bf16 ----------------------------------
__global__ __launch_bounds__(256) void wo_cvt_kernel(
    const float* __restrict__ Wo, unsigned short* __restrict__ Wob)
{
    size_t i = ((size_t)blockIdx.x * 256 + threadIdx.x) * 4;
    float4 v = *(const float4*)(Wo + i);
    u16x4 u;
    u[0] = f2bf(v.x); u[1] = f2bf(v.y); u[2] = f2bf(v.z); u[3] = f2bf(v.w);
    *(u16x4*)(Wob + i) = u;
}

// ---------------- kernel: QKV head projections via MFMA --------------------
// Q,K stored [n][h][s][64] bf16 (Q pre-scaled by QSCALE);
// V stored tiled [n][h][s/64][d][64] bf16.
__global__ __launch_bounds__(256) void proj_kernel(
    const float* __restrict__ qin, const float* __restrict__ kin, const float* __restrict__ vin,
    const float* __restrict__ Wq, const float* __restrict__ Wk, const float* __restrict__ Wv,
    unsigned short* __restrict__ Qb, unsigned short* __restrict__ Kb,
    unsigned short* __restrict__ Vt)
{
    __shared__ __align__(16) char tile[64 * 144];   // 64 rows x 144B (128B data + pad)

    int t3  = blockIdx.x >> 10;
    int rem = blockIdx.x & 1023;
    int h   = rem >> 6;
    int rt  = rem & 63;
    int wave = threadIdx.x >> 6, lane = threadIdx.x & 63;
    int quad = lane >> 4, l16 = lane & 15;

    const float* in = (t3 == 0) ? qin : ((t3 == 1) ? kin : vin);
    const float* W  = (t3 == 0) ? Wq  : ((t3 == 1) ? Wk  : Wv);

    int r0 = rt * 64 + wave * 16;   // global token row base for this wave

    bf16x8 bf0[4], bf1[4];
#pragma unroll
    for (int sl = 0; sl < 4; ++sl) {
        const float* wrow = W + (sl * 16 + l16) * 64;
        bf0[sl] = cvt8(wrow + quad * 8);
        bf1[sl] = cvt8(wrow + 32 + quad * 8);
    }
    const float* xrow = in + (size_t)(r0 + l16) * ED + h * 64;
    bf16x8 af0 = cvt8(xrow + quad * 8);
    bf16x8 af1 = cvt8(xrow + 32 + quad * 8);

    f32x4 acc[4];
#pragma unroll
    for (int sl = 0; sl < 4; ++sl) {
        f32x4 c = {0.f, 0.f, 0.f, 0.f};
        c = mfma16(af0, bf0[sl], c);
        c = mfma16(af1, bf1[sl], c);
        acc[sl] = c;
    }
    float sc = (t3 == 0) ? QSCALE : 1.0f;

    size_t nh = (size_t)((r0 >> 11) * HEADS + h);   // 64-row tile never straddles n
    int rl = lane >> 3, cl = lane & 7;              // readback row-in-group / 16B slot

    if (t3 != 2) {
        // ---- Q/K: LDS tile [s_local][e], wave-private rows, no barrier -----
#pragma unroll
        for (int r = 0; r < 4; ++r) {
            int srow = wave * 16 + quad * 4 + r;
#pragma unroll
            for (int sl = 0; sl < 4; ++sl)
                *(unsigned short*)(tile + srow * 144 + (sl * 16 + l16) * 2) =
                    f2bf(acc[sl][r] * sc);
        }
        unsigned short* dst = (t3 == 0) ? Qb : Kb;
        int s0 = (r0 & 2047);                        // this wave's first token row
#pragma unroll
        for (int g = 0; g < 2; ++g) {
            int lrow = wave * 16 + g * 8 + rl;
            uint4 v = *(const uint4*)(tile + lrow * 144 + cl * 16);
            *(uint4*)(dst + (nh * SEQ + (s0 & ~15) + g * 8 + rl) * HD + cl * 8) = v;
        }
    } else {
        // ---- V: LDS tile [e][s_local] (transpose), barrier across waves ----
#pragma unroll
        for (int r = 0; r < 4; ++r) {
            int srow = wave * 16 + quad * 4 + r;
#pragma unroll
            for (int sl = 0; sl < 4; ++sl)
                *(unsigned short*)(tile + (sl * 16 + l16) * 144 + srow * 2) =
                    f2bf(acc[sl][r]);
        }
        __syncthreads();
        int s_tile = rt & 31;
#pragma unroll
        for (int g = 0; g < 2; ++g) {
            int erow = wave * 16 + g * 8 + rl;
            uint4 v = *(const uint4*)(tile + erow * 144 + cl * 16);
            *(uint4*)(Vt + ((nh * 32 + s_tile) * 64 + erow) * 64 + cl * 8) = v;
        }
    }
}

// ---------------- kernel: flash attention, LDS-staged K/V, S^T scheme ------
// 256 threads = 4 waves x 32 queries = 128 q / block.
// QK^T computed transposed (A=K, B=Q -> D[key][q]); lane then holds 4
// CONSECUTIVE keys -> P written as ds_write_b64 (8/iter vs 32 b16).
// PV computed as O^T = V^T * P^T (A=V-frag, B=P^T b128 reads).
// SPLIT=1: grid 1024 (2 k-halves), partial f32 O + lsum out; else grid 512.
template <int SPLIT>
__global__ __launch_bounds__(256) void attn_kernel(
    const unsigned short* __restrict__ Qb, const unsigned short* __restrict__ Kb,
    const unsigned short* __restrict__ Vt2, const unsigned long long* __restrict__ mb,
    unsigned short* __restrict__ Ab, float* __restrict__ Of, float* __restrict__ Ls)
{
    __shared__ __align__(16) char smem[8192 + 8192 + 4 * 4608];  // K, V, P per wave

    int tid = threadIdx.x;
    int wave = tid >> 6, lane = tid & 63;
    int quad = lane >> 4, l16 = lane & 15;

    // XCD swizzle: 4 consecutive nh per XCD -> K/V resident in its L2
    int b   = blockIdx.x;
    int xcd = b & 7;
    int j   = b >> 3;
    int nh, qb, half;
    if (SPLIT) { nh = xcd * 4 + (j >> 5); int r = j & 31; qb = r >> 1; half = r & 1; }
    else       { nh = xcd * 4 + (j >> 4); qb = j & 15; half = 0; }
    int n = nh >> 4, h = nh & 15;
    int q0 = qb * 128 + wave * 32;          // this wave's 32 queries

    size_t headoff = (size_t)nh * SEQ * HD;
    bf16x8 qf[2][2];                         // B-operand now; same lane layout
#pragma unroll
    for (int t = 0; t < 2; ++t) {
        const unsigned short* qrow = Qb + headoff + (size_t)(q0 + t * 16 + l16) * HD;
        qf[t][0] = ldfrag(qrow + quad * 8);
        qf[t][1] = ldfrag(qrow + 32 + quad * 8);
    }

    // staging: per-lane source offset (bytes) with rotation ((slot - row)&7)
    int srow = lane >> 3, sslot = lane & 7;
    int stoff = srow * 128 + (((sslot - srow) & 7) * 16);

    // ds read address registers (bytes, loop-invariant)
    int rotA = ((quad + l16) & 7) * 16;
    int aK  = l16 * 128 + rotA;           // + kt*2048 imm ; ^64 -> high half
    int aKx = aK ^ 64;
    int aV  = 8192 + l16 * 128 + rotA;    // + sl*2048 imm ; ^64 -> key high half
    int aVx = aV ^ 64;
    char* pbase = smem + 16384 + wave * 4608;   // per-wave P region, + t*2304
    // P tile per (wave,t): [q=l16 row][64 keys], stride 144B.
    // write: row l16, byte kt*32 + quad*8 (b64, 4 keys packed)
    // read : row l16, byte kk*64 + quad*16 (b128)
    char* pw = pbase + l16 * 144 + quad * 8;
    char* pr = pbase + l16 * 144 + quad * 16;

    const unsigned short* gK = Kb + headoff;
    const unsigned short* gV = Vt2 + (size_t)nh * (32 * 4096);
    const unsigned long long* mbase = mb + (size_t)n * (SEQ * SEQ / 64)
                                         + (size_t)(q0 + l16) * (SEQ / 64);

    f32x4 o[2][4] = {{{0,0,0,0},{0,0,0,0},{0,0,0,0},{0,0,0,0}},
                     {{0,0,0,0},{0,0,0,0},{0,0,0,0},{0,0,0,0}}};
    float lsum[2] = {0.f, 0.f};
    int qsh = quad * 4;

    int kb0   = SPLIT ? half * (SEQ / 2) : 0;
    int kbend = SPLIT ? kb0 + (SEQ / 2) : SEQ;

    for (int kb = kb0; kb < kbend; kb += 64) {
        __syncthreads();   // all waves done reading previous tile
        // ---- stage K tile (8 KB) + V tile (8 KB): 4 chunks per wave --------
        const char* srcK = (const char*)(gK + (size_t)kb * 64) + stoff;
        const char* srcV = (const char*)(gV + (size_t)(kb >> 6) * 4096) + stoff;
#pragma unroll
        for (int i = 0; i < 4; ++i) {
            int c = wave * 4 + i;            // 0..15 (wave-uniform branch)
            if (c < 8) GLOAD_LDS(srcK + c * 1024, smem + c * 1024);
            else       GLOAD_LDS(srcV + (c - 8) * 1024, smem + 8192 + (c - 8) * 1024);
        }
        // mask rows: lane reads its q-row (q = q0 + t*16 + l16), pre-shift
        unsigned long long m64[2];
#pragma unroll
        for (int t = 0; t < 2; ++t)
            m64[t] = mbase[(size_t)(t * 16) * (SEQ / 64) + (kb >> 6)] >> qsh;
        __syncthreads();   // tile visible

        // ---- K fragments (A-operand) ---------------------------------------
        bf16x8 kf[4][2];
#pragma unroll
        for (int kt = 0; kt < 4; ++kt) {
            kf[kt][0] = ldfrag(smem + aK  + kt * 2048);
            kf[kt][1] = ldfrag(smem + aKx + kt * 2048);
        }
        // ---- S^T = K*Q^T ; mask+exp ; packed b64 P-writes ------------------
#pragma unroll
        for (int t = 0; t < 2; ++t) {
            f32x4 c[4];
#pragma unroll
            for (int kt = 0; kt < 4; ++kt) {
                f32x4 cc = {0.f, 0.f, 0.f, 0.f};
                cc = mfma16(kf[kt][0], qf[t][0], cc);
                cc = mfma16(kf[kt][1], qf[t][1], cc);
                c[kt] = cc;   // c[kt][r]: key = kb+kt*16+quad*4+r, q = q0+t*16+l16
            }
            unsigned mlo = (unsigned)m64[t];
            unsigned mhi = (unsigned)(m64[t] >> 32);
            float ls = 0.f;
#pragma unroll
            for (int kt = 0; kt < 4; ++kt) {
                unsigned mw = (kt & 2) ? mhi : mlo;
                int bs = (kt & 1) ? 16 : 0;
                float p0 = ((mw >> (bs + 0)) & 1u) ? __builtin_exp2f(c[kt][0]) : 0.f;
                float p1 = ((mw >> (bs + 1)) & 1u) ? __builtin_exp2f(c[kt][1]) : 0.f;
                float p2 = ((mw >> (bs + 2)) & 1u) ? __builtin_exp2f(c[kt][2]) : 0.f;
                float p3 = ((mw >> (bs + 3)) & 1u) ? __builtin_exp2f(c[kt][3]) : 0.f;
                ls += (p0 + p1) + (p2 + p3);
                uint2 dw = { packbf(p0, p1), packbf(p2, p3) };
                *(uint2*)(pw + t * 2304 + kt * 32) = dw;
            }
            lsum[t] += ls;
        }
        // ---- P^T B-fragments (per-wave region, in-wave ordering) -----------
        bf16x8 pb[2][2];
#pragma unroll
        for (int t = 0; t < 2; ++t) {
            pb[t][0] = ldfrag(pr + t * 2304);
            pb[t][1] = ldfrag(pr + t * 2304 + 64);
        }
        // ---- O^T = V^T * P^T : V-frags read once, reused across t ----------
#pragma unroll
        for (int sl = 0; sl < 4; ++sl) {
            bf16x8 va0 = ldfrag(smem + aV  + sl * 2048);
            bf16x8 va1 = ldfrag(smem + aVx + sl * 2048);
#pragma unroll
            for (int t = 0; t < 2; ++t) {
                o[t][sl] = mfma16(va0, pb[t][0], o[t][sl]);
                o[t][sl] = mfma16(va1, pb[t][1], o[t][sl]);
            }
        }
    }

    // ---- epilogue: O^T regs: o[t][sl][r] = O[q=q0+t*16+l16][d=sl*16+quad*4+r]
#pragma unroll
    for (int t = 0; t < 2; ++t) {
        float s = lsum[t];
        s += __shfl_xor(s, 16);
        s += __shfl_xor(s, 32);
        int q = q0 + t * 16 + l16;
        if (SPLIT) {
            size_t qg = (size_t)nh * SEQ + q;
            if (quad == 0) Ls[(size_t)half * 65536 + qg] = s;
            float* op = Of + ((size_t)half * 65536 + qg) * 64 + qsh;
#pragma unroll
            for (int sl = 0; sl < 4; ++sl) {
                float4 v = { o[t][sl][0], o[t][sl][1], o[t][sl][2], o[t][sl][3] };
                *(float4*)(op + sl * 16) = v;
            }
        } else {
            float rinv = 1.0f / s;
            unsigned short* op = Ab + (((size_t)(n * SEQ + q)) * HEADS + h) * HD + qsh;
#pragma unroll
            for (int sl = 0; sl < 4; ++sl) {
                u16x4 u;
                u[0] = f2bf(o[t][sl][0] * rinv);
                u[1] = f2bf(o[t][sl][1] * rinv);
                u[2] = f2bf(o[t][sl][2] * rinv);
                u[3] = f2bf(o[t][sl][3] * rinv);
                *(u16x4*)(op + sl * 16) = u;
            }
        }
    }
}

// ---------------- kernel: combine K-split halves ---------------------------
// Ab[(n*S+s)*H+h][d] = (O0+O1)/(l0+l1)
__global__ __launch_bounds__(256) void combine_kernel(
    const float* __restrict__ Of, const float* __restrict__ Ls,
    unsigned short* __restrict__ Ab)
{
    int idx = blockIdx.x * 256 + threadIdx.x;     // 1M threads, 4 floats each
    int q  = idx >> 4;                            // qglobal = nh*2048 + s
    int d0 = (idx & 15) * 4;
    const float4 o0 = *(const float4*)(Of + (size_t)q * 64 + d0);
    const float4 o1 = *(const float4*)(Of + 4194304 + (size_t)q * 64 + d0);
    float rl = 1.0f / (Ls[q] + Ls[65536 + q]);
    int n = q >> 15, h = (q >> 11) & 15, s = q & 2047;
    size_t ab = (((size_t)(n * SEQ + s)) * HEADS + h) * HD + d0;
    u16x4 u;
    u[0] = f2bf((o0.x + o1.x) * rl);
    u[1] = f2bf((o0.y + o1.y) * rl);
    u[2] = f2bf((o0.z + o1.z) * rl);
    u[3] = f2bf((o0.w + o1.w) * rl);
    *(u16x4*)(Ab + ab) = u;
}

// ---------------- kernel: out = Ab @ Wo^T + bo (m97-style) -----------------
// grid 256 = 32 row-tiles x 8 col-tiles of 128x128; 4 waves, each 64x64.
__global__ __launch_bounds__(256) void out_gemm_kernel(
    const unsigned short* __restrict__ Ab, const unsigned short* __restrict__ Wob,
    const float* __restrict__ bo, float* __restrict__ out)
{
    __shared__ __align__(16) char lds[32768];    // At 16KB + Bt 16KB (BK=64)

    int wave = threadIdx.x >> 6, lane = threadIdx.x & 63;
    int quad = lane >> 4, l16 = lane & 15;
    int rt = blockIdx.x >> 3, ct = blockIdx.x & 7;
    int wr = wave >> 1, wc = wave & 1;

    int srow = lane >> 3, sslot = lane & 7;
    int stoff = srow * 2048 + (((sslot - srow) & 7) * 16);
    const char* gA = (const char*)Ab  + (size_t)rt * 128 * 2048 + stoff;
    const char* gB = (const char*)Wob + (size_t)ct * 128 * 2048 + stoff;

    int aA[4], aB[4];
#pragma unroll
    for (int i = 0; i < 4; ++i) {
        int rowA = wr * 64 + i * 16 + l16;
        aA[i] = rowA * 128 + (((quad + rowA) & 7) * 16);
        int rowB = wc * 64 + i * 16 + l16;
        aB[i] = 16384 + rowB * 128 + (((quad + rowB) & 7) * 16);
    }

    f32x4 acc[4][4] = {};
    for (int f = 0; f < ED; f += 64) {
        __syncthreads();
#pragma unroll
        for (int i = 0; i < 4; ++i) {
            int c = wave * 4 + i;                     // 16 chunks of 8 rows
            GLOAD_LDS(gA + (size_t)c * 16384 + f * 2, lds + c * 1024);
            GLOAD_LDS(gB + (size_t)c * 16384 + f * 2, lds + 16384 + c * 1024);
        }
        __syncthreads();
#pragma unroll
        for (int kk = 0; kk < 2; ++kk) {
            int x = kk * 64;
            bf16x8 af[4], bfr[4];
#pragma unroll
            for (int i = 0; i < 4; ++i)  af[i]  = ldfrag(lds + (aA[i] ^ x));
#pragma unroll
            for (int sl = 0; sl < 4; ++sl) bfr[sl] = ldfrag(lds + (aB[sl] ^ x));
#pragma unroll
            for (int i = 0; i < 4; ++i)
#pragma unroll
                for (int sl = 0; sl < 4; ++sl)
                    acc[i][sl] = mfma16(af[i], bfr[sl], acc[i][sl]);
        }
    }

    float bv[4];
#pragma unroll
    for (int sl = 0; sl < 4; ++sl)
        bv[sl] = bo[ct * 128 + wc * 64 + sl * 16 + l16];
#pragma unroll
    for (int i = 0; i < 4; ++i)
#pragma unroll
        for (int r = 0; r < 4; ++r) {
            int row = rt * 128 + wr * 64 + i * 16 + quad * 4 + r;
#pragma unroll
            for (int sl = 0; sl < 4; ++sl) {
                int e = ct * 128 + wc * 64 + sl * 16 + l16;
                out[(size_t)row * ED + e] = acc[i][sl][r] + bv[sl];
            }
        }
}

// ---------------- launcher -------------------------------------------------
extern "C" void kernel_launch(void* const* d_in, const int* in_sizes, int n_in,
                              void* d_out, int out_size, void* d_ws, size_t ws_size,
                              hipStream_t stream)
{
    const float* values = (const float*)d_in[0];
    const float* keys   = (const float*)d_in[1];
    const float* query  = (const float*)d_in[2];
    const int*   mask   = (const int*)d_in[3];
    const float* Wv     = (const float*)d_in[4];
    const float* Wk     = (const float*)d_in[5];
    const float* Wq     = (const float*)d_in[6];
    const float* Wo     = (const float*)d_in[7];
    const float* bo     = (const float*)d_in[8];
    float* out = (float*)d_out;

    char* w = (char*)d_ws;
    unsigned short* Qb  = (unsigned short*)(w);              //  8 MB
    unsigned short* Kb  = (unsigned short*)(w +  8388608);   //  8 MB
    unsigned short* Vt  = (unsigned short*)(w + 16777216);   //  8 MB tiled V
    unsigned short* Ab  = (unsigned short*)(w + 25165824);   //  8 MB
    unsigned long long* Mb = (unsigned long long*)(w + 33554432); // 1 MB
    unsigned short* Wob = (unsigned short*)(w + 34603008);   //  2 MB
    float* Of = (float*)(w + 36700160);                      // 33.5 MB (split)
    float* Ls = (float*)(w + 70254592);                      // 0.5 MB  (split)

    bool split = ws_size >= 70778880ULL;

    mask_bits_kernel<<<NB * SEQ * SEQ / 256, 256, 0, stream>>>(mask, Mb);
    wo_cvt_kernel<<<ED * ED / (256 * 4), 256, 0, stream>>>(Wo, Wob);
    proj_kernel<<<3 * HEADS * 64, 256, 0, stream>>>(query, keys, values, Wq, Wk, Wv, Qb, Kb, Vt);
    if (split) {
        attn_kernel<1><<<1024, 256, 0, stream>>>(Qb, Kb, Vt, Mb, Ab, Of, Ls);
        combine_kernel<<<4096, 256, 0, stream>>>(Of, Ls, Ab);
    } else {
        attn_kernel<0><<<512, 256, 0, stream>>>(Qb, Kb, Vt, Mb, Ab, Of, Ls);
    }
    out_gemm_kernel<<<256, 256, 0, stream>>>(Ab, Wob, bo, out);
}

// Round 7
// 252.621 us; speedup vs baseline: 1.8989x; 1.0222x over previous
//
#include <hip/hip_runtime.h>
#include <hip/hip_bf16.h>

// Problem constants
#define NB 2
#define SEQ 2048
#define HEADS 16
#define HD 64
#define ED 1024

typedef __bf16 bf16x8 __attribute__((ext_vector_type(8)));
typedef float f32x4 __attribute__((ext_vector_type(4)));
typedef unsigned short u16x8 __attribute__((ext_vector_type(8)));
typedef unsigned short u16x4 __attribute__((ext_vector_type(4)));

__device__ __forceinline__ unsigned short f2bf(float f) {
    unsigned u = __builtin_bit_cast(unsigned, f);
    u += 0x7fffu + ((u >> 16) & 1u);   // RNE
    return (unsigned short)(u >> 16);
}

__device__ __forceinline__ bf16x8 cvt8(const float* __restrict__ p) {
    const float4* p4 = (const float4*)p;
    float4 a = p4[0], b = p4[1];
    u16x8 u;
    u[0] = f2bf(a.x); u[1] = f2bf(a.y); u[2] = f2bf(a.z); u[3] = f2bf(a.w);
    u[4] = f2bf(b.x); u[5] = f2bf(b.y); u[6] = f2bf(b.z); u[7] = f2bf(b.w);
    return __builtin_bit_cast(bf16x8, u);
}

__device__ __forceinline__ bf16x8 ldfrag(const void* p) {
    uint4 v = *(const uint4*)p;
    return __builtin_bit_cast(bf16x8, v);
}

__device__ __forceinline__ f32x4 mfma16(bf16x8 a, bf16x8 b, f32x4 c) {
    return __builtin_amdgcn_mfma_f32_16x16x32_bf16(a, b, c, 0, 0, 0);
}

// pack two positive f32 into bf16 pair (round-half-up): 2 adds + v_perm
__device__ __forceinline__ unsigned packbf(float lo, float hi) {
    unsigned a = __builtin_bit_cast(unsigned, hi) + 0x8000u;
    unsigned b = __builtin_bit_cast(unsigned, lo) + 0x8000u;
    return __builtin_amdgcn_perm(a, b, 0x07060302u);   // [hi16(a) : hi16(b)]
}

#define GLOAD_LDS(gp, lp) \
    __builtin_amdgcn_global_load_lds( \
        (const __attribute__((address_space(1))) unsigned int*)(gp), \
        (__attribute__((address_space(3))) unsigned int*)(lp), 16, 0, 0)

// softmax scale folded into Q at projection: (1/sqrt(1024)) * log2(e)
#define QSCALE 0.04508422f

// ---------------- kernel: pack mask int32 -> bitmask (1 bit/elem) ----------
__global__ __launch_bounds__(256) void mask_bits_kernel(
    const int* __restrict__ mask, unsigned long long* __restrict__ bits)
{
    size_t i = (size_t)blockIdx.x * 256 + threadIdx.x;
    int m = mask[i];
    unsigned long long b = __ballot(m != 0);
    if ((threadIdx.x & 63) == 0) bits[i >> 6] = b;
}

// ---------------- kernel: Wo fp32 -> bf16 ----------------------------------
__global__ __launch_bounds__(256) void wo_cvt_kernel(
    const float* __restrict__ Wo, unsigned short* __restrict__ Wob)
{
    size_t i = ((size_t)blockIdx.x * 256 + threadIdx.x) * 4;
    float4 v = *(const float4*)(Wo + i);
    u16x4 u;
    u[0] = f2bf(v.x); u[1] = f2bf(v.y); u[2] = f2bf(v.z); u[3] = f2bf(v.w);
    *(u16x4*)(Wob + i) = u;
}

// ---------------- kernel: QKV head projections via MFMA --------------------
// Q,K stored [n][h][s][64] bf16 (Q pre-scaled by QSCALE);
// V stored tiled [n][h][s/64][d][64] bf16.
__global__ __launch_bounds__(256) void proj_kernel(
    const float* __restrict__ qin, const float* __restrict__ kin, const float* __restrict__ vin,
    const float* __restrict__ Wq, const float* __restrict__ Wk, const float* __restrict__ Wv,
    unsigned short* __restrict__ Qb, unsigned short* __restrict__ Kb,
    unsigned short* __restrict__ Vt)
{
    __shared__ __align__(16) char tile[64 * 144];   // 64 rows x 144B (128B data + pad)

    int t3  = blockIdx.x >> 10;
    int rem = blockIdx.x & 1023;
    int h   = rem >> 6;
    int rt  = rem & 63;
    int wave = threadIdx.x >> 6, lane = threadIdx.x & 63;
    int quad = lane >> 4, l16 = lane & 15;

    const float* in = (t3 == 0) ? qin : ((t3 == 1) ? kin : vin);
    const float* W  = (t3 == 0) ? Wq  : ((t3 == 1) ? Wk  : Wv);

    int r0 = rt * 64 + wave * 16;   // global token row base for this wave

    bf16x8 bf0[4], bf1[4];
#pragma unroll
    for (int sl = 0; sl < 4; ++sl) {
        const float* wrow = W + (sl * 16 + l16) * 64;
        bf0[sl] = cvt8(wrow + quad * 8);
        bf1[sl] = cvt8(wrow + 32 + quad * 8);
    }
    const float* xrow = in + (size_t)(r0 + l16) * ED + h * 64;
    bf16x8 af0 = cvt8(xrow + quad * 8);
    bf16x8 af1 = cvt8(xrow + 32 + quad * 8);

    f32x4 acc[4];
#pragma unroll
    for (int sl = 0; sl < 4; ++sl) {
        f32x4 c = {0.f, 0.f, 0.f, 0.f};
        c = mfma16(af0, bf0[sl], c);
        c = mfma16(af1, bf1[sl], c);
        acc[sl] = c;
    }
    float sc = (t3 == 0) ? QSCALE : 1.0f;

    size_t nh = (size_t)((r0 >> 11) * HEADS + h);   // 64-row tile never straddles n
    int rl = lane >> 3, cl = lane & 7;              // readback row-in-group / 16B slot

    if (t3 != 2) {
        // ---- Q/K: LDS tile [s_local][e], wave-private rows, no barrier -----
#pragma unroll
        for (int r = 0; r < 4; ++r) {
            int srow = wave * 16 + quad * 4 + r;
#pragma unroll
            for (int sl = 0; sl < 4; ++sl)
                *(unsigned short*)(tile + srow * 144 + (sl * 16 + l16) * 2) =
                    f2bf(acc[sl][r] * sc);
        }
        unsigned short* dst = (t3 == 0) ? Qb : Kb;
        int s0 = (r0 & 2047);                        // this wave's first token row
#pragma unroll
        for (int g = 0; g < 2; ++g) {
            int lrow = wave * 16 + g * 8 + rl;
            uint4 v = *(const uint4*)(tile + lrow * 144 + cl * 16);
            *(uint4*)(dst + (nh * SEQ + (s0 & ~15) + g * 8 + rl) * HD + cl * 8) = v;
        }
    } else {
        // ---- V: LDS tile [e][s_local] (transpose), barrier across waves ----
#pragma unroll
        for (int r = 0; r < 4; ++r) {
            int srow = wave * 16 + quad * 4 + r;
#pragma unroll
            for (int sl = 0; sl < 4; ++sl)
                *(unsigned short*)(tile + (sl * 16 + l16) * 144 + srow * 2) =
                    f2bf(acc[sl][r]);
        }
        __syncthreads();
        int s_tile = rt & 31;
#pragma unroll
        for (int g = 0; g < 2; ++g) {
            int erow = wave * 16 + g * 8 + rl;
            uint4 v = *(const uint4*)(tile + erow * 144 + cl * 16);
            *(uint4*)(Vt + ((nh * 32 + s_tile) * 64 + erow) * 64 + cl * 8) = v;
        }
    }
}

// ---------------- kernel: flash attention, pipelined LDS staging -----------
// 256 threads = 4 waves x 32 queries = 128 q / block.
// K double-buffered, V single-buffered; both prefetched with >=0.7-iter lead
// so no barrier ever drains a fresh global_load_lds (m97 stall removed).
// S^T scheme (A=K, B=Q); P round-trip via per-wave LDS tile; row-sums via
// all-ones MFMA (quad-uniform -> no shuffle reduction).
// SPLIT=1: grid 1024 (2 k-halves), partial f32 O + lsum out; else grid 512.
template <int SPLIT>
__global__ __launch_bounds__(256, 4) void attn_kernel(
    const unsigned short* __restrict__ Qb, const unsigned short* __restrict__ Kb,
    const unsigned short* __restrict__ Vt2, const unsigned long long* __restrict__ mb,
    unsigned short* __restrict__ Ab, float* __restrict__ Of, float* __restrict__ Ls)
{
    // K buf0 @0, K buf1 @8192, V @16384, P @24576 + wave*2304
    __shared__ __align__(16) char smem[24576 + 4 * 2304];

    int tid = threadIdx.x;
    int wave = tid >> 6, lane = tid & 63;
    int quad = lane >> 4, l16 = lane & 15;

    // XCD swizzle: 4 consecutive nh per XCD -> K/V resident in its L2
    int b   = blockIdx.x;
    int xcd = b & 7;
    int j   = b >> 3;
    int nh, qb, half;
    if (SPLIT) { nh = xcd * 4 + (j >> 5); int r = j & 31; qb = r >> 1; half = r & 1; }
    else       { nh = xcd * 4 + (j >> 4); qb = j & 15; half = 0; }
    int n = nh >> 4, h = nh & 15;
    int q0 = qb * 128 + wave * 32;          // this wave's 32 queries

    size_t headoff = (size_t)nh * SEQ * HD;
    bf16x8 qf[2][2];                         // B-operand
#pragma unroll
    for (int t = 0; t < 2; ++t) {
        const unsigned short* qrow = Qb + headoff + (size_t)(q0 + t * 16 + l16) * HD;
        qf[t][0] = ldfrag(qrow + quad * 8);
        qf[t][1] = ldfrag(qrow + 32 + quad * 8);
    }

    // staging: per-lane source offset (bytes) with rotation ((slot - row)&7)
    int srow = lane >> 3, sslot = lane & 7;
    int stoff = srow * 128 + (((sslot - srow) & 7) * 16);

    // ds read address registers (bytes, loop-invariant)
    int rotA = ((quad + l16) & 7) * 16;
    int aK0 = l16 * 128 + rotA;           // + par*8192 + kt*2048 ; ^64 high half
    int aV  = 16384 + l16 * 128 + rotA;   // + sl*2048 ; ^64 key high half
    int aVx = aV ^ 64;
    char* pbase = smem + 24576 + wave * 2304;   // shared across t (in-wave order)
    char* pw = pbase + l16 * 144 + quad * 8;
    char* pr = pbase + l16 * 144 + quad * 16;

    const unsigned short* gK = Kb + headoff;
    const unsigned short* gV = Vt2 + (size_t)nh * (32 * 4096);
    const unsigned long long* mbase = mb + (size_t)n * (SEQ * SEQ / 64)
                                         + (size_t)(q0 + l16) * (SEQ / 64);

    // all-ones bf16 A-fragment for row sums
    u16x8 ou;
#pragma unroll
    for (int jj = 0; jj < 8; ++jj) ou[jj] = 0x3F80;
    bf16x8 ones = __builtin_bit_cast(bf16x8, ou);

    f32x4 o[2][4] = {{{0,0,0,0},{0,0,0,0},{0,0,0,0},{0,0,0,0}},
                     {{0,0,0,0},{0,0,0,0},{0,0,0,0},{0,0,0,0}}};
    f32x4 lacc[2] = {{0,0,0,0},{0,0,0,0}};
    int qsh = quad * 4;

    int kb0   = SPLIT ? half * (SEQ / 2) : 0;
    int kbend = SPLIT ? kb0 + (SEQ / 2) : SEQ;

    // ---- prologue: stage K_0 -> buf0, V_0 -> Vbuf --------------------------
    {
        const char* sK = (const char*)(gK + (size_t)kb0 * 64) + stoff;
        const char* sV = (const char*)(gV + (size_t)(kb0 >> 6) * 4096) + stoff;
#pragma unroll
        for (int i2 = 0; i2 < 2; ++i2) {
            int c = wave * 2 + i2;
            GLOAD_LDS(sK + c * 1024, smem + c * 1024);
            GLOAD_LDS(sV + c * 1024, smem + 16384 + c * 1024);
        }
    }

    int par = 0;
    for (int kb = kb0; kb < kbend; kb += 64) {
        int kbn = (kb + 64) & (SEQ - 1);   // wrapped next tile (harmless at end)
        __syncthreads();   // (a) K_i, V_i visible; drains long-lead prefetches
        // ---- prefetch K_{i+1} into the other K buffer ----------------------
        {
            const char* sK = (const char*)(gK + (size_t)kbn * 64) + stoff;
            char* dK = smem + (par ^ 1) * 8192;
#pragma unroll
            for (int i2 = 0; i2 < 2; ++i2) {
                int c = wave * 2 + i2;
                GLOAD_LDS(sK + c * 1024, dK + c * 1024);
            }
        }
        // mask rows (L2-hot), pre-shifted by quad
        unsigned long long m64[2];
#pragma unroll
        for (int t = 0; t < 2; ++t)
            m64[t] = mbase[(size_t)(t * 16) * (SEQ / 64) + (kb >> 6)] >> qsh;

        // ---- K fragments (A-operand) from current buffer -------------------
        const char* kbuf = smem + par * 8192;
        bf16x8 kf[4][2];
#pragma unroll
        for (int kt = 0; kt < 4; ++kt) {
            kf[kt][0] = ldfrag(kbuf + aK0 + kt * 2048);
            kf[kt][1] = ldfrag(kbuf + (aK0 ^ 64) + kt * 2048);
        }
        // ---- per q-subtile: S^T=K*Q^T, mask+exp, P round-trip, sums, PV ----
#pragma unroll
        for (int t = 0; t < 2; ++t) {
            f32x4 c[4];
#pragma unroll
            for (int kt = 0; kt < 4; ++kt) {
                f32x4 cc = {0.f, 0.f, 0.f, 0.f};
                cc = mfma16(kf[kt][0], qf[t][0], cc);
                cc = mfma16(kf[kt][1], qf[t][1], cc);
                c[kt] = cc;   // c[kt][r]: key = kb+kt*16+quad*4+r, q = q0+t*16+l16
            }
            unsigned mlo = (unsigned)m64[t];
            unsigned mhi = (unsigned)(m64[t] >> 32);
#pragma unroll
            for (int kt = 0; kt < 4; ++kt) {
                unsigned mw = (kt & 2) ? mhi : mlo;
                int bs = (kt & 1) ? 16 : 0;
                float p0 = ((mw >> (bs + 0)) & 1u) ? __builtin_exp2f(c[kt][0]) : 0.f;
                float p1 = ((mw >> (bs + 1)) & 1u) ? __builtin_exp2f(c[kt][1]) : 0.f;
                float p2 = ((mw >> (bs + 2)) & 1u) ? __builtin_exp2f(c[kt][2]) : 0.f;
                float p3 = ((mw >> (bs + 3)) & 1u) ? __builtin_exp2f(c[kt][3]) : 0.f;
                uint2 dw = { packbf(p0, p1), packbf(p2, p3) };
                *(uint2*)(pw + kt * 32) = dw;
            }
            // P^T B-fragments (in-wave write->read ordering via lgkmcnt)
            bf16x8 pb0 = ldfrag(pr);
            bf16x8 pb1 = ldfrag(pr + 64);
            // row sums on the matrix pipe (quad-uniform result)
            lacc[t] = mfma16(ones, pb0, lacc[t]);
            lacc[t] = mfma16(ones, pb1, lacc[t]);
            // O^T = V^T * P^T
#pragma unroll
            for (int sl = 0; sl < 4; ++sl) {
                o[t][sl] = mfma16(ldfrag(smem + aV  + sl * 2048), pb0, o[t][sl]);
                o[t][sl] = mfma16(ldfrag(smem + aVx + sl * 2048), pb1, o[t][sl]);
            }
        }
        __syncthreads();   // (b) PV reads done; drains K_{i+1} (~0.7-iter lead)
        // ---- prefetch V_{i+1} (arrives by next barrier (a)) ----------------
        {
            const char* sV = (const char*)(gV + (size_t)(kbn >> 6) * 4096) + stoff;
#pragma unroll
            for (int i2 = 0; i2 < 2; ++i2) {
                int c = wave * 2 + i2;
                GLOAD_LDS(sV + c * 1024, smem + 16384 + c * 1024);
            }
        }
        par ^= 1;
    }

    // ---- epilogue: o[t][sl][r] = O[q=q0+t*16+l16][d=sl*16+quad*4+r] --------
#pragma unroll
    for (int t = 0; t < 2; ++t) {
        float s = lacc[t][0];               // row-sum, uniform across quads
        int q = q0 + t * 16 + l16;
        if (SPLIT) {
            size_t qg = (size_t)nh * SEQ + q;
            if (quad == 0) Ls[(size_t)half * 65536 + qg] = s;
            float* op = Of + ((size_t)half * 65536 + qg) * 64 + qsh;
#pragma unroll
            for (int sl = 0; sl < 4; ++sl) {
                float4 v = { o[t][sl][0], o[t][sl][1], o[t][sl][2], o[t][sl][3] };
                *(float4*)(op + sl * 16) = v;
            }
        } else {
            float rinv = 1.0f / s;
            unsigned short* op = Ab + (((size_t)(n * SEQ + q)) * HEADS + h) * HD + qsh;
#pragma unroll
            for (int sl = 0; sl < 4; ++sl) {
                u16x4 u;
                u[0] = f2bf(o[t][sl][0] * rinv);
                u[1] = f2bf(o[t][sl][1] * rinv);
                u[2] = f2bf(o[t][sl][2] * rinv);
                u[3] = f2bf(o[t][sl][3] * rinv);
                *(u16x4*)(op + sl * 16) = u;
            }
        }
    }
}

// ---------------- kernel: combine K-split halves ---------------------------
// Ab[(n*S+s)*H+h][d] = (O0+O1)/(l0+l1)
__global__ __launch_bounds__(256) void combine_kernel(
    const float* __restrict__ Of, const float* __restrict__ Ls,
    unsigned short* __restrict__ Ab)
{
    int idx = blockIdx.x * 256 + threadIdx.x;     // 1M threads, 4 floats each
    int q  = idx >> 4;                            // qglobal = nh*2048 + s
    int d0 = (idx & 15) * 4;
    const float4 o0 = *(const float4*)(Of + (size_t)q * 64 + d0);
    const float4 o1 = *(const float4*)(Of + 4194304 + (size_t)q * 64 + d0);
    float rl = 1.0f / (Ls[q] + Ls[65536 + q]);
    int n = q >> 15, h = (q >> 11) & 15, s = q & 2047;
    size_t ab = (((size_t)(n * SEQ + s)) * HEADS + h) * HD + d0;
    u16x4 u;
    u[0] = f2bf((o0.x + o1.x) * rl);
    u[1] = f2bf((o0.y + o1.y) * rl);
    u[2] = f2bf((o0.z + o1.z) * rl);
    u[3] = f2bf((o0.w + o1.w) * rl);
    *(u16x4*)(Ab + ab) = u;
}

// ---------------- kernel: out = Ab @ Wo^T + bo (m97-style) -----------------
// grid 256 = 32 row-tiles x 8 col-tiles of 128x128; 4 waves, each 64x64.
__global__ __launch_bounds__(256) void out_gemm_kernel(
    const unsigned short* __restrict__ Ab, const unsigned short* __restrict__ Wob,
    const float* __restrict__ bo, float* __restrict__ out)
{
    __shared__ __align__(16) char lds[32768];    // At 16KB + Bt 16KB (BK=64)

    int wave = threadIdx.x >> 6, lane = threadIdx.x & 63;
    int quad = lane >> 4, l16 = lane & 15;
    int rt = blockIdx.x >> 3, ct = blockIdx.x & 7;
    int wr = wave >> 1, wc = wave & 1;

    int srow = lane >> 3, sslot = lane & 7;
    int stoff = srow * 2048 + (((sslot - srow) & 7) * 16);
    const char* gA = (const char*)Ab  + (size_t)rt * 128 * 2048 + stoff;
    const char* gB = (const char*)Wob + (size_t)ct * 128 * 2048 + stoff;

    int aA[4], aB[4];
#pragma unroll
    for (int i = 0; i < 4; ++i) {
        int rowA = wr * 64 + i * 16 + l16;
        aA[i] = rowA * 128 + (((quad + rowA) & 7) * 16);
        int rowB = wc * 64 + i * 16 + l16;
        aB[i] = 16384 + rowB * 128 + (((quad + rowB) & 7) * 16);
    }

    f32x4 acc[4][4] = {};
    for (int f = 0; f < ED; f += 64) {
        __syncthreads();
#pragma unroll
        for (int i = 0; i < 4; ++i) {
            int c = wave * 4 + i;                     // 16 chunks of 8 rows
            GLOAD_LDS(gA + (size_t)c * 16384 + f * 2, lds + c * 1024);
            GLOAD_LDS(gB + (size_t)c * 16384 + f * 2, lds + 16384 + c * 1024);
        }
        __syncthreads();
#pragma unroll
        for (int kk = 0; kk < 2; ++kk) {
            int x = kk * 64;
            bf16x8 af[4], bfr[4];
#pragma unroll
            for (int i = 0; i < 4; ++i)  af[i]  = ldfrag(lds + (aA[i] ^ x));
#pragma unroll
            for (int sl = 0; sl < 4; ++sl) bfr[sl] = ldfrag(lds + (aB[sl] ^ x));
#pragma unroll
            for (int i = 0; i < 4; ++i)
#pragma unroll
                for (int sl = 0; sl < 4; ++sl)
                    acc[i][sl] = mfma16(af[i], bfr[sl], acc[i][sl]);
        }
    }

    float bv[4];
#pragma unroll
    for (int sl = 0; sl < 4; ++sl)
        bv[sl] = bo[ct * 128 + wc * 64 + sl * 16 + l16];
#pragma unroll
    for (int i = 0; i < 4; ++i)
#pragma unroll
        for (int r = 0; r < 4; ++r) {
            int row = rt * 128 + wr * 64 + i * 16 + quad * 4 + r;
#pragma unroll
            for (int sl = 0; sl < 4; ++sl) {
                int e = ct * 128 + wc * 64 + sl * 16 + l16;
                out[(size_t)row * ED + e] = acc[i][sl][r] + bv[sl];
            }
        }
}

// ---------------- launcher -------------------------------------------------
extern "C" void kernel_launch(void* const* d_in, const int* in_sizes, int n_in,
                              void* d_out, int out_size, void* d_ws, size_t ws_size,
                              hipStream_t stream)
{
    const float* values = (const float*)d_in[0];
    const float* keys   = (const float*)d_in[1];
    const float* query  = (const float*)d_in[2];
    const int*   mask   = (const int*)d_in[3];
    const float* Wv     = (const float*)d_in[4];
    const float* Wk     = (const float*)d_in[5];
    const float* Wq     = (const float*)d_in[6];
    const float* Wo     = (const float*)d_in[7];
    const float* bo     = (const float*)d_in[8];
    float* out = (float*)d_out;

    char* w = (char*)d_ws;
    unsigned short* Qb  = (unsigned short*)(w);              //  8 MB
    unsigned short* Kb  = (unsigned short*)(w +  8388608);   //  8 MB
    unsigned short* Vt  = (unsigned short*)(w + 16777216);   //  8 MB tiled V
    unsigned short* Ab  = (unsigned short*)(w + 25165824);   //  8 MB
    unsigned long long* Mb = (unsigned long long*)(w + 33554432); // 1 MB
    unsigned short* Wob = (unsigned short*)(w + 34603008);   //  2 MB
    float* Of = (float*)(w + 36700160);                      // 33.5 MB (split)
    float* Ls = (float*)(w + 70254592);                      // 0.5 MB  (split)

    bool split = ws_size >= 70778880ULL;

    mask_bits_kernel<<<NB * SEQ * SEQ / 256, 256, 0, stream>>>(mask, Mb);
    wo_cvt_kernel<<<ED * ED / (256 * 4), 256, 0, stream>>>(Wo, Wob);
    proj_kernel<<<3 * HEADS * 64, 256, 0, stream>>>(query, keys, values, Wq, Wk, Wv, Qb, Kb, Vt);
    if (split) {
        attn_kernel<1><<<1024, 256, 0, stream>>>(Qb, Kb, Vt, Mb, Ab, Of, Ls);
        combine_kernel<<<4096, 256, 0, stream>>>(Of, Ls, Ab);
    } else {
        attn_kernel<0><<<512, 256, 0, stream>>>(Qb, Kb, Vt, Mb, Ab, Of, Ls);
    }
    out_gemm_kernel<<<256, 256, 0, stream>>>(Ab, Wob, bo, out);
}